// Round 10
// baseline (237.118 us; speedup 1.0000x reference)
//
#include <hip/hip_runtime.h>
#include <hip/hip_bf16.h>

#define N_NODES 100000
#define NB 784   // buckets of 128 nodes: 784*128 = 100352 >= N_NODES
#define NPAD 100352
#define BSH 7
#define BMASK 127
#define CAP 4096  // static per-bucket capacity (mean 2040, sigma ~45 -> safe)
#define APAD 68   // padded LDS row stride (floats)

__device__ inline void fma4(float a, const float4& w, float4& c) {
  c.x = fmaf(a, w.x, c.x);
  c.y = fmaf(a, w.y, c.y);
  c.z = fmaf(a, w.z, c.z);
  c.w = fmaf(a, w.w, c.w);
}
__device__ inline unsigned short f2bf(float f) {  // RNE f32->bf16
  unsigned u = __float_as_uint(f);
  u += 0x7fffu + ((u >> 16) & 1u);
  return (unsigned short)(u >> 16);
}
__device__ inline float bflo(unsigned u) { return __uint_as_float(u << 16); }
__device__ inline float bfhi(unsigned u) { return __uint_as_float(u & 0xffff0000u); }

// ---------------------------------------------------------------------------
// bscatter: packed edges (src<<7 | dst&127) into static bucket regions
// ep[b*CAP .. b*CAP+cnt_b). Per-block LDS ranks; one global atomic per
// (bucket, block) -> block-private contiguous write runs. bcur = counts.
// ---------------------------------------------------------------------------
__global__ __launch_bounds__(256) void bscatter_k(const int* __restrict__ src,
                                                  const int* __restrict__ dst,
                                                  unsigned* __restrict__ bcur,
                                                  unsigned* __restrict__ ep,
                                                  int E) {
  __shared__ unsigned lh[NB];
  __shared__ unsigned lbase[NB];
  for (int i = threadIdx.x; i < NB; i += 256) lh[i] = 0;
  __syncthreads();
  const int base = blockIdx.x * 4096;
  unsigned short rank[16];
  unsigned short bb[16];
#pragma unroll
  for (int it = 0; it < 16; ++it) {
    int e = base + it * 256 + threadIdx.x;
    if (e < E) {
      unsigned b = ((unsigned)dst[e]) >> BSH;
      bb[it] = (unsigned short)b;
      rank[it] = (unsigned short)atomicAdd(&lh[b], 1u);
    }
  }
  __syncthreads();
  for (int i = threadIdx.x; i < NB; i += 256)
    lbase[i] = lh[i] ? atomicAdd(&bcur[i], lh[i]) : 0u;
  __syncthreads();
#pragma unroll
  for (int it = 0; it < 16; ++it) {
    int e = base + it * 256 + threadIdx.x;
    if (e < E) {
      unsigned b = bb[it];
      ep[(size_t)b * CAP + lbase[b] + rank[it]] =
          (((unsigned)src[e]) << BSH) | (((unsigned)dst[e]) & BMASK);
    }
  }
}

// ---------------------------------------------------------------------------
// Fused kernel: blocks [0, GB1) run the layer-1 dual-GEMM
//   xn = x@W1n (bf16), xs = x@W1s + b1 (f32);
// blocks [GB1, GB1+NB) counting-sort their bucket (independent work overlap).
// Shared memory is a union: gemm body uses 50176 B, sort body 1 KB.
// ---------------------------------------------------------------------------
#define GB1 1563  // ceil(100000/64)

__global__ __launch_bounds__(256) void fused1_k(
    const float* __restrict__ x, const float* __restrict__ W1n,
    const float* __restrict__ W1s, const float* __restrict__ b1,
    unsigned short* __restrict__ xnb, float* __restrict__ xs,
    const unsigned* __restrict__ ep, const unsigned* __restrict__ bcur,
    int* __restrict__ ssrc, uint2* __restrict__ rows2, int M) {
  __shared__ __align__(16) float smem[12544];  // 50176 B
  const int tid = threadIdx.x;

  if (blockIdx.x >= GB1) {
    // ---------------- bsort body: bucket b ----------------
    const int b = blockIdx.x - GB1;
    unsigned* cnt = (unsigned*)smem;
    unsigned* sc = cnt + 128;
    const unsigned cntb = bcur[b];
    const unsigned beg = (unsigned)(b * CAP);
    if (tid < 128) cnt[tid] = 0;
    __syncthreads();
    for (unsigned j = tid; j < cntb; j += 256)
      atomicAdd(&cnt[ep[(size_t)beg + j] & BMASK], 1u);
    __syncthreads();
    unsigned v = (tid < 128) ? cnt[tid] : 0u;
    if (tid < 128) sc[tid] = v;
    __syncthreads();
    for (int off = 1; off < 128; off <<= 1) {
      unsigned t = (tid < 128 && tid >= off) ? sc[tid - off] : 0u;
      __syncthreads();
      if (tid < 128) sc[tid] += t;
      __syncthreads();
    }
    if (tid < 128) {
      unsigned ex = sc[tid] - v;
      rows2[b * 128 + tid] = make_uint2(beg + ex, beg + ex + v);
      cnt[tid] = ex;
    }
    __syncthreads();
    for (unsigned j = tid; j < cntb; j += 256) {
      unsigned p = ep[(size_t)beg + j];
      unsigned r = atomicAdd(&cnt[p & BMASK], 1u);
      ssrc[(size_t)beg + r] = (int)(p >> BSH);
    }
    return;
  }

  // ---------------- gemm1 body ----------------
  float* Wn = smem;         // 4096 floats
  float* Ws = smem + 4096;  // 4096 floats
  float* Ax = smem + 8192;  // 64*APAD = 4352 floats
  const int row0 = blockIdx.x * 64;

  for (int i = tid; i < 1024; i += 256) {
    ((float4*)Wn)[i] = ((const float4*)W1n)[i];
    ((float4*)Ws)[i] = ((const float4*)W1s)[i];
  }
  for (int i = tid; i < 1024; i += 256) {
    int r = i >> 4, c = i & 15;
    long long gr = row0 + r;
    if (gr >= M) gr = M - 1;
    float4 v = ((const float4*)(x + gr * 64))[c];
    *(float4*)&Ax[r * APAD + 4 * c] = v;
  }
  __syncthreads();

  const int tx = tid & 15;
  const int ty = tid >> 4;
  const int arow = ty * 4;

  float4 an[4], as[4];
#pragma unroll
  for (int r = 0; r < 4; ++r) {
    an[r] = make_float4(0.f, 0.f, 0.f, 0.f);
    as[r] = make_float4(0.f, 0.f, 0.f, 0.f);
  }

#pragma unroll 1
  for (int k4 = 0; k4 < 16; ++k4) {
    float4 wn0 = *(const float4*)&Wn[(4 * k4 + 0) * 64 + 4 * tx];
    float4 wn1 = *(const float4*)&Wn[(4 * k4 + 1) * 64 + 4 * tx];
    float4 wn2 = *(const float4*)&Wn[(4 * k4 + 2) * 64 + 4 * tx];
    float4 wn3 = *(const float4*)&Wn[(4 * k4 + 3) * 64 + 4 * tx];
    float4 ws0 = *(const float4*)&Ws[(4 * k4 + 0) * 64 + 4 * tx];
    float4 ws1 = *(const float4*)&Ws[(4 * k4 + 1) * 64 + 4 * tx];
    float4 ws2 = *(const float4*)&Ws[(4 * k4 + 2) * 64 + 4 * tx];
    float4 ws3 = *(const float4*)&Ws[(4 * k4 + 3) * 64 + 4 * tx];
#pragma unroll
    for (int r = 0; r < 4; ++r) {
      float4 a = *(const float4*)&Ax[(arow + r) * APAD + 4 * k4];
      fma4(a.x, wn0, an[r]);
      fma4(a.y, wn1, an[r]);
      fma4(a.z, wn2, an[r]);
      fma4(a.w, wn3, an[r]);
      fma4(a.x, ws0, as[r]);
      fma4(a.y, ws1, as[r]);
      fma4(a.z, ws2, as[r]);
      fma4(a.w, ws3, as[r]);
    }
  }

  const float4 bv = *(const float4*)&b1[4 * tx];
#pragma unroll
  for (int r = 0; r < 4; ++r) {
    int row = row0 + arow + r;
    if (row < M) {
      float4 o;
      o.x = as[r].x + bv.x;
      o.y = as[r].y + bv.y;
      o.z = as[r].z + bv.z;
      o.w = as[r].w + bv.w;
      *(float4*)&xs[(long long)row * 64 + 4 * tx] = o;
      ushort4 p;
      p.x = f2bf(an[r].x);
      p.y = f2bf(an[r].y);
      p.z = f2bf(an[r].z);
      p.w = f2bf(an[r].w);
      *(ushort4*)&xnb[(long long)row * 64 + 4 * tx] = p;
    }
  }
}

// ---------------------------------------------------------------------------
// Layer-2 dual-GEMM over h: hn = h@W2n (bf16 out), hs = h@W2s + b2 (f32).
// Block tile 128r x 32c, thread tile 4x4x2; h staged in LDS.
// ---------------------------------------------------------------------------
__global__ __launch_bounds__(256) void gemm2_k(
    const float* __restrict__ h, const float* __restrict__ W2n,
    const float* __restrict__ W2s, const float* __restrict__ b2,
    unsigned short* __restrict__ hnb, float* __restrict__ hs, int M) {
  __shared__ float Wn[64 * 32];
  __shared__ float Ws[64 * 32];
  __shared__ float Ah[128 * APAD];
  const int tid = threadIdx.x;
  const int row0 = blockIdx.x * 128;

  for (int i = tid; i < 512; i += 256) {
    ((float4*)Wn)[i] = ((const float4*)W2n)[i];
    ((float4*)Ws)[i] = ((const float4*)W2s)[i];
  }
  for (int i = tid; i < 2048; i += 256) {
    int r = i >> 4, c = i & 15;
    long long gr = row0 + r;
    if (gr >= M) gr = M - 1;
    float4 v = ((const float4*)(h + gr * 64))[c];
    *(float4*)&Ah[r * APAD + 4 * c] = v;
  }
  __syncthreads();

  const int tx = tid & 7;
  const int ty = tid >> 3;
  const int arow = ty * 4;

  float4 an[4], as[4];
#pragma unroll
  for (int r = 0; r < 4; ++r) {
    an[r] = make_float4(0.f, 0.f, 0.f, 0.f);
    as[r] = make_float4(0.f, 0.f, 0.f, 0.f);
  }

#pragma unroll 1
  for (int k4 = 0; k4 < 16; ++k4) {
    float4 wn0 = *(const float4*)&Wn[(4 * k4 + 0) * 32 + 4 * tx];
    float4 wn1 = *(const float4*)&Wn[(4 * k4 + 1) * 32 + 4 * tx];
    float4 wn2 = *(const float4*)&Wn[(4 * k4 + 2) * 32 + 4 * tx];
    float4 wn3 = *(const float4*)&Wn[(4 * k4 + 3) * 32 + 4 * tx];
    float4 ws0 = *(const float4*)&Ws[(4 * k4 + 0) * 32 + 4 * tx];
    float4 ws1 = *(const float4*)&Ws[(4 * k4 + 1) * 32 + 4 * tx];
    float4 ws2 = *(const float4*)&Ws[(4 * k4 + 2) * 32 + 4 * tx];
    float4 ws3 = *(const float4*)&Ws[(4 * k4 + 3) * 32 + 4 * tx];
#pragma unroll
    for (int r = 0; r < 4; ++r) {
      float4 a = *(const float4*)&Ah[(arow + r) * APAD + 4 * k4];
      fma4(a.x, wn0, an[r]);
      fma4(a.y, wn1, an[r]);
      fma4(a.z, wn2, an[r]);
      fma4(a.w, wn3, an[r]);
      fma4(a.x, ws0, as[r]);
      fma4(a.y, ws1, as[r]);
      fma4(a.z, ws2, as[r]);
      fma4(a.w, ws3, as[r]);
    }
  }

  const float4 bv = *(const float4*)&b2[4 * tx];
#pragma unroll
  for (int r = 0; r < 4; ++r) {
    int row = row0 + arow + r;
    if (row < M) {
      float4 o;
      o.x = as[r].x + bv.x;
      o.y = as[r].y + bv.y;
      o.z = as[r].z + bv.z;
      o.w = as[r].w + bv.w;
      *(float4*)&hs[(long long)row * 32 + 4 * tx] = o;
      ushort4 p;
      p.x = f2bf(an[r].x);
      p.y = f2bf(an[r].y);
      p.z = f2bf(an[r].z);
      p.w = f2bf(an[r].w);
      *(ushort4*)&hnb[(long long)row * 32 + 4 * tx] = p;
    }
  }
}

// ---------------------------------------------------------------------------
// bf16 gather-mean, uint4 (8 bf16 = 16B) per lane, P = F/8 lanes per node:
//   out[node][:] = act( mean_j valb[ssrc[j]][:] + base[node][:] )
// Bulk loop unpredicated (groups of 8 loads in flight); clamped tail group.
// ---------------------------------------------------------------------------
template <int LOGF, bool RELU>
__global__ __launch_bounds__(256) void gatherb_k(
    const uint4* __restrict__ valb4, const int* __restrict__ ssrc,
    const uint2* __restrict__ rows2, const float* __restrict__ base,
    float* __restrict__ out, int N) {
  constexpr int P = (1 << LOGF) / 8;  // uint4s per row: 8 (F=64) / 4 (F=32)
  const int node = blockIdx.x * (256 / P) + threadIdx.x / P;
  const int p = threadIdx.x & (P - 1);
  if (node >= N) return;
  const uint2 be = rows2[node];
  const unsigned beg = be.x, end = be.y;

  float acc[8];
#pragma unroll
  for (int q = 0; q < 8; ++q) acc[q] = 0.f;

  unsigned j = beg;
  for (; j + 8 <= end; j += 8) {
    int sn[8];
#pragma unroll
    for (int i = 0; i < 8; ++i) sn[i] = ssrc[j + i];
    uint4 u[8];
#pragma unroll
    for (int i = 0; i < 8; ++i) u[i] = valb4[(size_t)sn[i] * P + p];
#pragma unroll
    for (int i = 0; i < 8; ++i) {
      acc[0] += bflo(u[i].x);
      acc[1] += bfhi(u[i].x);
      acc[2] += bflo(u[i].y);
      acc[3] += bfhi(u[i].y);
      acc[4] += bflo(u[i].z);
      acc[5] += bfhi(u[i].z);
      acc[6] += bflo(u[i].w);
      acc[7] += bfhi(u[i].w);
    }
  }
  if (j < end) {
    const unsigned last = end - 1;
    int sn[8];
#pragma unroll
    for (int i = 0; i < 8; ++i) {
      unsigned jj = j + i;
      sn[i] = ssrc[jj < last ? jj : last];
    }
    uint4 u[8];
#pragma unroll
    for (int i = 0; i < 8; ++i) u[i] = valb4[(size_t)sn[i] * P + p];
#pragma unroll
    for (int i = 0; i < 8; ++i) {
      bool ok = (j + i) < end;
      acc[0] += ok ? bflo(u[i].x) : 0.f;
      acc[1] += ok ? bfhi(u[i].x) : 0.f;
      acc[2] += ok ? bflo(u[i].y) : 0.f;
      acc[3] += ok ? bfhi(u[i].y) : 0.f;
      acc[4] += ok ? bflo(u[i].z) : 0.f;
      acc[5] += ok ? bfhi(u[i].z) : 0.f;
      acc[6] += ok ? bflo(u[i].w) : 0.f;
      acc[7] += ok ? bfhi(u[i].w) : 0.f;
    }
  }

  const unsigned dg = end - beg;
  const float inv = dg ? 1.f / (float)dg : 0.f;
  const size_t o = (size_t)node * (8 * P) + 8 * p;
  float4 b0 = *(const float4*)&base[o];
  float4 b1 = *(const float4*)&base[o + 4];
  float4 o0, o1;
  o0.x = acc[0] * inv + b0.x;
  o0.y = acc[1] * inv + b0.y;
  o0.z = acc[2] * inv + b0.z;
  o0.w = acc[3] * inv + b0.w;
  o1.x = acc[4] * inv + b1.x;
  o1.y = acc[5] * inv + b1.y;
  o1.z = acc[6] * inv + b1.z;
  o1.w = acc[7] * inv + b1.w;
  if (RELU) {
    o0.x = fmaxf(o0.x, 0.f);
    o0.y = fmaxf(o0.y, 0.f);
    o0.z = fmaxf(o0.z, 0.f);
    o0.w = fmaxf(o0.w, 0.f);
    o1.x = fmaxf(o1.x, 0.f);
    o1.y = fmaxf(o1.y, 0.f);
    o1.z = fmaxf(o1.z, 0.f);
    o1.w = fmaxf(o1.w, 0.f);
  }
  *(float4*)&out[o] = o0;
  *(float4*)&out[o + 4] = o1;
}

extern "C" void kernel_launch(void* const* d_in, const int* in_sizes, int n_in,
                              void* d_out, int out_size, void* d_ws,
                              size_t ws_size, hipStream_t stream) {
  const float* x   = (const float*)d_in[0];
  const int*   ei  = (const int*)d_in[1];  // [2, E]: row0 = src, row1 = dst
  const float* W1n = (const float*)d_in[2];
  const float* W1s = (const float*)d_in[3];
  const float* b1  = (const float*)d_in[4];
  const float* W2n = (const float*)d_in[5];
  const float* W2s = (const float*)d_in[6];
  const float* b2  = (const float*)d_in[7];
  float* out = (float*)d_out;

  const int E = in_sizes[1] / 2;  // 1,600,000
  const int M = N_NODES;
  const int* src = ei;
  const int* dst = ei + E;

  // Workspace layout (bytes):
  //   ep    @ 0           12,845,056  (NB*CAP u32, static bucket regions)
  //   ssrc  @ 12,845,056  12,845,056
  //   rows2 @ 25,690,112     802,816  (NPAD uint2)
  //   bcur  @ 26,492,928       3,136
  //   xnb   @ 26,496,064  12,800,000  (bf16 M x 64; layer2: hnb bf16 M x 32)
  //   xs    @ 39,296,064  25,600,000  (f32 M x 64;  layer2: hs f32 M x 32)
  //   h     @ 64,896,064  25,600,000  (f32 M x 64)
  char* wsb = (char*)d_ws;
  unsigned*       ep    = (unsigned*)(wsb);
  int*            ssrc  = (int*)(wsb + 12845056);
  uint2*          rows2 = (uint2*)(wsb + 25690112);
  unsigned*       bcur  = (unsigned*)(wsb + 26492928);
  unsigned short* xnb   = (unsigned short*)(wsb + 26496064);
  float*          xs    = (float*)(wsb + 39296064);
  float*          h     = (float*)(wsb + 64896064);
  unsigned short* hnb   = xnb;  // layer-2 reuse
  float*          hs    = xs;   // layer-2 reuse

  // 1) zero bucket cursors (3 KB)
  hipMemsetAsync(bcur, 0, NB * 4, stream);
  // 2) scatter edges into static bucket regions
  bscatter_k<<<(E + 4095) / 4096, 256, 0, stream>>>(src, dst, bcur, ep, E);
  // 3) fused: layer-1 dual-GEMM (blocks 0..GB1) + per-bucket counting sort
  fused1_k<<<GB1 + NB, 256, 0, stream>>>(x, W1n, W1s, b1, xnb, xs, ep, bcur,
                                         ssrc, rows2, M);
  // 4) h = relu(mean(xn[src]) + xs)
  gatherb_k<6, true><<<(M + 31) / 32, 256, 0, stream>>>(
      (const uint4*)xnb, ssrc, rows2, xs, h, M);
  // 5) hn(bf16)/hs = h@{W2n,W2s}+b2
  gemm2_k<<<(M + 127) / 128, 256, 0, stream>>>(h, W2n, W2s, b2, hnb, hs, M);
  // 6) out = mean(hn[src]) + hs
  gatherb_k<5, false><<<(M + 63) / 64, 256, 0, stream>>>(
      (const uint4*)hnb, ssrc, rows2, hs, out, M);
}

// Round 11
// 236.436 us; speedup vs baseline: 1.0029x; 1.0029x over previous
//
#include <hip/hip_runtime.h>
#include <hip/hip_bf16.h>

#define N_NODES 100000
#define NB 784   // buckets of 128 nodes: 784*128 = 100352 >= N_NODES
#define NPAD 100352
#define BSH 7
#define BMASK 127
#define CAP 4096  // static per-bucket capacity (mean 2040 -> safe)
#define APAD 68   // padded LDS row stride (floats)

__device__ inline void fma4(float a, const float4& w, float4& c) {
  c.x = fmaf(a, w.x, c.x);
  c.y = fmaf(a, w.y, c.y);
  c.z = fmaf(a, w.z, c.z);
  c.w = fmaf(a, w.w, c.w);
}
__device__ inline unsigned short f2bf(float f) {  // RNE f32->bf16
  unsigned u = __float_as_uint(f);
  u += 0x7fffu + ((u >> 16) & 1u);
  return (unsigned short)(u >> 16);
}
__device__ inline unsigned pack2bf(float a, float b) {
  return (unsigned)f2bf(a) | ((unsigned)f2bf(b) << 16);
}
__device__ inline float bflo(unsigned u) { return __uint_as_float(u << 16); }
__device__ inline float bfhi(unsigned u) { return __uint_as_float(u & 0xffff0000u); }
__device__ inline float bf2f(unsigned short u) {
  return __uint_as_float((unsigned)u << 16);
}

// ---------------------------------------------------------------------------
// bscatter (1024 threads, R9-proven line coalescing): packed edges
// (src<<7 | dst&127) into static bucket regions ep[b*CAP .. b*CAP+cnt_b).
// ---------------------------------------------------------------------------
__global__ __launch_bounds__(1024) void bscatter_k(const int* __restrict__ src,
                                                   const int* __restrict__ dst,
                                                   unsigned* __restrict__ bcur,
                                                   unsigned* __restrict__ ep,
                                                   int E) {
  __shared__ unsigned lh[NB];
  __shared__ unsigned lbase[NB];
  for (int i = threadIdx.x; i < NB; i += 1024) lh[i] = 0;
  __syncthreads();
  const int base = blockIdx.x * 16384;
  unsigned short rank[16];
  unsigned short bb[16];
#pragma unroll
  for (int it = 0; it < 16; ++it) {
    int e = base + it * 1024 + threadIdx.x;
    if (e < E) {
      unsigned b = ((unsigned)dst[e]) >> BSH;
      bb[it] = (unsigned short)b;
      rank[it] = (unsigned short)atomicAdd(&lh[b], 1u);
    }
  }
  __syncthreads();
  for (int i = threadIdx.x; i < NB; i += 1024)
    lbase[i] = lh[i] ? atomicAdd(&bcur[i], lh[i]) : 0u;
  __syncthreads();
#pragma unroll
  for (int it = 0; it < 16; ++it) {
    int e = base + it * 1024 + threadIdx.x;
    if (e < E) {
      unsigned b = bb[it];
      ep[(size_t)b * CAP + lbase[b] + rank[it]] =
          (((unsigned)src[e]) << BSH) | (((unsigned)dst[e]) & BMASK);
    }
  }
}

// ---------------------------------------------------------------------------
// Fused: blocks [0,GB1) = layer-1 dual-GEMM (xn bf16 + xs f32);
// blocks [GB1,GB1+NB) = per-bucket counting sort (independent; overlaps).
// ---------------------------------------------------------------------------
#define GB1 1563  // ceil(100000/64)

__global__ __launch_bounds__(256) void fused1_k(
    const float* __restrict__ x, const float* __restrict__ W1n,
    const float* __restrict__ W1s, const float* __restrict__ b1,
    unsigned short* __restrict__ xnb, float* __restrict__ xs,
    const unsigned* __restrict__ ep, const unsigned* __restrict__ bcur,
    int* __restrict__ ssrc, uint2* __restrict__ rows2, int M) {
  __shared__ __align__(16) float smem[12544];  // 50176 B
  const int tid = threadIdx.x;

  if (blockIdx.x >= GB1) {
    // ---------------- bsort body: bucket b ----------------
    const int b = blockIdx.x - GB1;
    unsigned* cnt = (unsigned*)smem;
    unsigned* sc = cnt + 128;
    const unsigned cntb = bcur[b];
    const unsigned beg = (unsigned)(b * CAP);
    if (tid < 128) cnt[tid] = 0;
    __syncthreads();
    for (unsigned j = tid; j < cntb; j += 256)
      atomicAdd(&cnt[ep[(size_t)beg + j] & BMASK], 1u);
    __syncthreads();
    unsigned v = (tid < 128) ? cnt[tid] : 0u;
    if (tid < 128) sc[tid] = v;
    __syncthreads();
    for (int off = 1; off < 128; off <<= 1) {
      unsigned t = (tid < 128 && tid >= off) ? sc[tid - off] : 0u;
      __syncthreads();
      if (tid < 128) sc[tid] += t;
      __syncthreads();
    }
    if (tid < 128) {
      unsigned ex = sc[tid] - v;
      rows2[b * 128 + tid] = make_uint2(beg + ex, beg + ex + v);
      cnt[tid] = ex;
    }
    __syncthreads();
    for (unsigned j = tid; j < cntb; j += 256) {
      unsigned p = ep[(size_t)beg + j];
      unsigned r = atomicAdd(&cnt[p & BMASK], 1u);
      ssrc[(size_t)beg + r] = (int)(p >> BSH);
    }
    return;
  }

  // ---------------- gemm1 body ----------------
  float* Wn = smem;
  float* Ws = smem + 4096;
  float* Ax = smem + 8192;  // 64*APAD
  const int row0 = blockIdx.x * 64;

  for (int i = tid; i < 1024; i += 256) {
    ((float4*)Wn)[i] = ((const float4*)W1n)[i];
    ((float4*)Ws)[i] = ((const float4*)W1s)[i];
  }
  for (int i = tid; i < 1024; i += 256) {
    int r = i >> 4, c = i & 15;
    long long gr = row0 + r;
    if (gr >= M) gr = M - 1;
    float4 v = ((const float4*)(x + gr * 64))[c];
    *(float4*)&Ax[r * APAD + 4 * c] = v;
  }
  __syncthreads();

  const int tx = tid & 15;
  const int ty = tid >> 4;
  const int arow = ty * 4;

  float4 an[4], as[4];
#pragma unroll
  for (int r = 0; r < 4; ++r) {
    an[r] = make_float4(0.f, 0.f, 0.f, 0.f);
    as[r] = make_float4(0.f, 0.f, 0.f, 0.f);
  }

#pragma unroll 1
  for (int k4 = 0; k4 < 16; ++k4) {
    float4 wn0 = *(const float4*)&Wn[(4 * k4 + 0) * 64 + 4 * tx];
    float4 wn1 = *(const float4*)&Wn[(4 * k4 + 1) * 64 + 4 * tx];
    float4 wn2 = *(const float4*)&Wn[(4 * k4 + 2) * 64 + 4 * tx];
    float4 wn3 = *(const float4*)&Wn[(4 * k4 + 3) * 64 + 4 * tx];
    float4 ws0 = *(const float4*)&Ws[(4 * k4 + 0) * 64 + 4 * tx];
    float4 ws1 = *(const float4*)&Ws[(4 * k4 + 1) * 64 + 4 * tx];
    float4 ws2 = *(const float4*)&Ws[(4 * k4 + 2) * 64 + 4 * tx];
    float4 ws3 = *(const float4*)&Ws[(4 * k4 + 3) * 64 + 4 * tx];
#pragma unroll
    for (int r = 0; r < 4; ++r) {
      float4 a = *(const float4*)&Ax[(arow + r) * APAD + 4 * k4];
      fma4(a.x, wn0, an[r]);
      fma4(a.y, wn1, an[r]);
      fma4(a.z, wn2, an[r]);
      fma4(a.w, wn3, an[r]);
      fma4(a.x, ws0, as[r]);
      fma4(a.y, ws1, as[r]);
      fma4(a.z, ws2, as[r]);
      fma4(a.w, ws3, as[r]);
    }
  }

  const float4 bv = *(const float4*)&b1[4 * tx];
#pragma unroll
  for (int r = 0; r < 4; ++r) {
    int row = row0 + arow + r;
    if (row < M) {
      float4 o;
      o.x = as[r].x + bv.x;
      o.y = as[r].y + bv.y;
      o.z = as[r].z + bv.z;
      o.w = as[r].w + bv.w;
      *(float4*)&xs[(long long)row * 64 + 4 * tx] = o;
      ushort4 p;
      p.x = f2bf(an[r].x);
      p.y = f2bf(an[r].y);
      p.z = f2bf(an[r].z);
      p.w = f2bf(an[r].w);
      *(ushort4*)&xnb[(long long)row * 64 + 4 * tx] = p;
    }
  }
}

// ---------------------------------------------------------------------------
// gather1: mean1[node][:] = mean_j xnb[ssrc[j]][:]  -> bf16 (no epilogue;
// relu(mean+xs) is fused into gemm2's staging). P=8 lanes/node, uint4 loads.
// ---------------------------------------------------------------------------
__global__ __launch_bounds__(256) void gather1_k(
    const uint4* __restrict__ valb4, const int* __restrict__ ssrc,
    const uint2* __restrict__ rows2, uint4* __restrict__ meanb, int N) {
  constexpr int P = 8;
  const int node = blockIdx.x * (256 / P) + threadIdx.x / P;
  const int p = threadIdx.x & (P - 1);
  if (node >= N) return;
  const uint2 be = rows2[node];
  const unsigned beg = be.x, end = be.y;

  float acc[8];
#pragma unroll
  for (int q = 0; q < 8; ++q) acc[q] = 0.f;

  unsigned j = beg;
  for (; j + 8 <= end; j += 8) {
    int sn[8];
#pragma unroll
    for (int i = 0; i < 8; ++i) sn[i] = ssrc[j + i];
    uint4 u[8];
#pragma unroll
    for (int i = 0; i < 8; ++i) u[i] = valb4[(size_t)sn[i] * P + p];
#pragma unroll
    for (int i = 0; i < 8; ++i) {
      acc[0] += bflo(u[i].x);
      acc[1] += bfhi(u[i].x);
      acc[2] += bflo(u[i].y);
      acc[3] += bfhi(u[i].y);
      acc[4] += bflo(u[i].z);
      acc[5] += bfhi(u[i].z);
      acc[6] += bflo(u[i].w);
      acc[7] += bfhi(u[i].w);
    }
  }
  if (j < end) {
    const unsigned last = end - 1;
    int sn[8];
#pragma unroll
    for (int i = 0; i < 8; ++i) {
      unsigned jj = j + i;
      sn[i] = ssrc[jj < last ? jj : last];
    }
    uint4 u[8];
#pragma unroll
    for (int i = 0; i < 8; ++i) u[i] = valb4[(size_t)sn[i] * P + p];
#pragma unroll
    for (int i = 0; i < 8; ++i) {
      bool ok = (j + i) < end;
      acc[0] += ok ? bflo(u[i].x) : 0.f;
      acc[1] += ok ? bfhi(u[i].x) : 0.f;
      acc[2] += ok ? bflo(u[i].y) : 0.f;
      acc[3] += ok ? bfhi(u[i].y) : 0.f;
      acc[4] += ok ? bflo(u[i].z) : 0.f;
      acc[5] += ok ? bfhi(u[i].z) : 0.f;
      acc[6] += ok ? bflo(u[i].w) : 0.f;
      acc[7] += ok ? bfhi(u[i].w) : 0.f;
    }
  }

  const unsigned dg = end - beg;
  const float inv = dg ? 1.f / (float)dg : 0.f;
  uint4 pk;
  pk.x = pack2bf(acc[0] * inv, acc[1] * inv);
  pk.y = pack2bf(acc[2] * inv, acc[3] * inv);
  pk.z = pack2bf(acc[4] * inv, acc[5] * inv);
  pk.w = pack2bf(acc[6] * inv, acc[7] * inv);
  meanb[(size_t)node * P + p] = pk;
}

// ---------------------------------------------------------------------------
// Layer-2 dual-GEMM with fused h: stages Ah = relu(mean1(bf16) + xs) in LDS,
// then hn = Ah@W2n (bf16 out), hs = Ah@W2s + b2 (f32).
// ---------------------------------------------------------------------------
__global__ __launch_bounds__(256) void gemm2_k(
    const unsigned short* __restrict__ mean1, const float* __restrict__ xs,
    const float* __restrict__ W2n, const float* __restrict__ W2s,
    const float* __restrict__ b2, unsigned short* __restrict__ hnb,
    float* __restrict__ hs, int M) {
  __shared__ float Wn[64 * 32];
  __shared__ float Ws[64 * 32];
  __shared__ float Ah[128 * APAD];
  const int tid = threadIdx.x;
  const int row0 = blockIdx.x * 128;

  for (int i = tid; i < 512; i += 256) {
    ((float4*)Wn)[i] = ((const float4*)W2n)[i];
    ((float4*)Ws)[i] = ((const float4*)W2s)[i];
  }
  for (int i = tid; i < 2048; i += 256) {
    int r = i >> 4, c = i & 15;
    long long gr = row0 + r;
    if (gr >= M) gr = M - 1;
    float4 sv = ((const float4*)(xs + gr * 64))[c];
    ushort4 mv = ((const ushort4*)(mean1 + gr * 64))[c];
    float4 v;
    v.x = fmaxf(bf2f(mv.x) + sv.x, 0.f);
    v.y = fmaxf(bf2f(mv.y) + sv.y, 0.f);
    v.z = fmaxf(bf2f(mv.z) + sv.z, 0.f);
    v.w = fmaxf(bf2f(mv.w) + sv.w, 0.f);
    *(float4*)&Ah[r * APAD + 4 * c] = v;
  }
  __syncthreads();

  const int tx = tid & 7;
  const int ty = tid >> 3;
  const int arow = ty * 4;

  float4 an[4], as[4];
#pragma unroll
  for (int r = 0; r < 4; ++r) {
    an[r] = make_float4(0.f, 0.f, 0.f, 0.f);
    as[r] = make_float4(0.f, 0.f, 0.f, 0.f);
  }

#pragma unroll 1
  for (int k4 = 0; k4 < 16; ++k4) {
    float4 wn0 = *(const float4*)&Wn[(4 * k4 + 0) * 32 + 4 * tx];
    float4 wn1 = *(const float4*)&Wn[(4 * k4 + 1) * 32 + 4 * tx];
    float4 wn2 = *(const float4*)&Wn[(4 * k4 + 2) * 32 + 4 * tx];
    float4 wn3 = *(const float4*)&Wn[(4 * k4 + 3) * 32 + 4 * tx];
    float4 ws0 = *(const float4*)&Ws[(4 * k4 + 0) * 32 + 4 * tx];
    float4 ws1 = *(const float4*)&Ws[(4 * k4 + 1) * 32 + 4 * tx];
    float4 ws2 = *(const float4*)&Ws[(4 * k4 + 2) * 32 + 4 * tx];
    float4 ws3 = *(const float4*)&Ws[(4 * k4 + 3) * 32 + 4 * tx];
#pragma unroll
    for (int r = 0; r < 4; ++r) {
      float4 a = *(const float4*)&Ah[(arow + r) * APAD + 4 * k4];
      fma4(a.x, wn0, an[r]);
      fma4(a.y, wn1, an[r]);
      fma4(a.z, wn2, an[r]);
      fma4(a.w, wn3, an[r]);
      fma4(a.x, ws0, as[r]);
      fma4(a.y, ws1, as[r]);
      fma4(a.z, ws2, as[r]);
      fma4(a.w, ws3, as[r]);
    }
  }

  const float4 bv = *(const float4*)&b2[4 * tx];
#pragma unroll
  for (int r = 0; r < 4; ++r) {
    int row = row0 + arow + r;
    if (row < M) {
      float4 o;
      o.x = as[r].x + bv.x;
      o.y = as[r].y + bv.y;
      o.z = as[r].z + bv.z;
      o.w = as[r].w + bv.w;
      *(float4*)&hs[(long long)row * 32 + 4 * tx] = o;
      ushort4 p;
      p.x = f2bf(an[r].x);
      p.y = f2bf(an[r].y);
      p.z = f2bf(an[r].z);
      p.w = f2bf(an[r].w);
      *(ushort4*)&hnb[(long long)row * 32 + 4 * tx] = p;
    }
  }
}

// ---------------------------------------------------------------------------
// gather2: out[node][:] = mean_j hnb[ssrc[j]][:] + hs[node][:]  (f32 out)
// P=4 lanes/node (32 bf16 row), uint4 loads.
// ---------------------------------------------------------------------------
__global__ __launch_bounds__(256) void gather2_k(
    const uint4* __restrict__ valb4, const int* __restrict__ ssrc,
    const uint2* __restrict__ rows2, const float* __restrict__ base,
    float* __restrict__ out, int N) {
  constexpr int P = 4;
  const int node = blockIdx.x * (256 / P) + threadIdx.x / P;
  const int p = threadIdx.x & (P - 1);
  if (node >= N) return;
  const uint2 be = rows2[node];
  const unsigned beg = be.x, end = be.y;

  float acc[8];
#pragma unroll
  for (int q = 0; q < 8; ++q) acc[q] = 0.f;

  unsigned j = beg;
  for (; j + 8 <= end; j += 8) {
    int sn[8];
#pragma unroll
    for (int i = 0; i < 8; ++i) sn[i] = ssrc[j + i];
    uint4 u[8];
#pragma unroll
    for (int i = 0; i < 8; ++i) u[i] = valb4[(size_t)sn[i] * P + p];
#pragma unroll
    for (int i = 0; i < 8; ++i) {
      acc[0] += bflo(u[i].x);
      acc[1] += bfhi(u[i].x);
      acc[2] += bflo(u[i].y);
      acc[3] += bfhi(u[i].y);
      acc[4] += bflo(u[i].z);
      acc[5] += bfhi(u[i].z);
      acc[6] += bflo(u[i].w);
      acc[7] += bfhi(u[i].w);
    }
  }
  if (j < end) {
    const unsigned last = end - 1;
    int sn[8];
#pragma unroll
    for (int i = 0; i < 8; ++i) {
      unsigned jj = j + i;
      sn[i] = ssrc[jj < last ? jj : last];
    }
    uint4 u[8];
#pragma unroll
    for (int i = 0; i < 8; ++i) u[i] = valb4[(size_t)sn[i] * P + p];
#pragma unroll
    for (int i = 0; i < 8; ++i) {
      bool ok = (j + i) < end;
      acc[0] += ok ? bflo(u[i].x) : 0.f;
      acc[1] += ok ? bfhi(u[i].x) : 0.f;
      acc[2] += ok ? bflo(u[i].y) : 0.f;
      acc[3] += ok ? bfhi(u[i].y) : 0.f;
      acc[4] += ok ? bflo(u[i].z) : 0.f;
      acc[5] += ok ? bfhi(u[i].z) : 0.f;
      acc[6] += ok ? bflo(u[i].w) : 0.f;
      acc[7] += ok ? bfhi(u[i].w) : 0.f;
    }
  }

  const unsigned dg = end - beg;
  const float inv = dg ? 1.f / (float)dg : 0.f;
  const size_t o = (size_t)node * 32 + 8 * p;
  float4 b0 = *(const float4*)&base[o];
  float4 b1 = *(const float4*)&base[o + 4];
  float4 o0, o1;
  o0.x = acc[0] * inv + b0.x;
  o0.y = acc[1] * inv + b0.y;
  o0.z = acc[2] * inv + b0.z;
  o0.w = acc[3] * inv + b0.w;
  o1.x = acc[4] * inv + b1.x;
  o1.y = acc[5] * inv + b1.y;
  o1.z = acc[6] * inv + b1.z;
  o1.w = acc[7] * inv + b1.w;
  *(float4*)&out[o] = o0;
  *(float4*)&out[o + 4] = o1;
}

extern "C" void kernel_launch(void* const* d_in, const int* in_sizes, int n_in,
                              void* d_out, int out_size, void* d_ws,
                              size_t ws_size, hipStream_t stream) {
  const float* x   = (const float*)d_in[0];
  const int*   ei  = (const int*)d_in[1];  // [2, E]: row0 = src, row1 = dst
  const float* W1n = (const float*)d_in[2];
  const float* W1s = (const float*)d_in[3];
  const float* b1  = (const float*)d_in[4];
  const float* W2n = (const float*)d_in[5];
  const float* W2s = (const float*)d_in[6];
  const float* b2  = (const float*)d_in[7];
  float* out = (float*)d_out;

  const int E = in_sizes[1] / 2;  // 1,600,000
  const int M = N_NODES;
  const int* src = ei;
  const int* dst = ei + E;

  // Workspace layout (bytes):
  //   ep    @ 0           12,845,056  (NB*CAP u32; layer2: hnb bf16 Mx32 aliases)
  //   ssrc  @ 12,845,056  12,845,056
  //   rows2 @ 25,690,112     802,816
  //   bcur  @ 26,492,928       3,136
  //   xnb   @ 26,496,064  12,800,000  (bf16 M x 64)
  //   xs    @ 39,296,064  25,600,000  (f32 M x 64)
  //   mean1 @ 64,896,064  12,800,000  (bf16 M x 64; layer2: hs f32 Mx32
  //                                    row-exact alias, written by gemm2 after
  //                                    staging its own rows)
  char* wsb = (char*)d_ws;
  unsigned*       ep    = (unsigned*)(wsb);
  int*            ssrc  = (int*)(wsb + 12845056);
  uint2*          rows2 = (uint2*)(wsb + 25690112);
  unsigned*       bcur  = (unsigned*)(wsb + 26492928);
  unsigned short* xnb   = (unsigned short*)(wsb + 26496064);
  float*          xs    = (float*)(wsb + 39296064);
  unsigned short* mean1 = (unsigned short*)(wsb + 64896064);
  unsigned short* hnb   = (unsigned short*)(wsb);            // aliases ep (dead)
  float*          hs    = (float*)(wsb + 64896064);          // row-aliases mean1

  // 1) zero bucket cursors (3 KB)
  hipMemsetAsync(bcur, 0, NB * 4, stream);
  // 2) scatter edges into static bucket regions (1024-thr: coalesced runs)
  bscatter_k<<<(E + 16383) / 16384, 1024, 0, stream>>>(src, dst, bcur, ep, E);
  // 3) fused: layer-1 dual-GEMM + per-bucket counting sort
  fused1_k<<<GB1 + NB, 256, 0, stream>>>(x, W1n, W1s, b1, xnb, xs, ep, bcur,
                                         ssrc, rows2, M);
  // 4) mean1(bf16) = mean(xn[src])   (h-fusion: no xs read, no h write)
  gather1_k<<<(M + 31) / 32, 256, 0, stream>>>((const uint4*)xnb, ssrc, rows2,
                                               (uint4*)mean1, M);
  // 5) gemm2 stages relu(mean1+xs) in LDS; hn(bf16)/hs = Ah@{W2n,W2s}+b2
  gemm2_k<<<(M + 127) / 128, 256, 0, stream>>>(mean1, xs, W2n, W2s, b2, hnb,
                                               hs, M);
  // 6) out = mean(hn[src]) + hs
  gather2_k<<<(M + 63) / 64, 256, 0, stream>>>((const uint4*)hnb, ssrc, rows2,
                                               hs, out, M);
}

// Round 12
// 230.064 us; speedup vs baseline: 1.0307x; 1.0277x over previous
//
#include <hip/hip_runtime.h>
#include <hip/hip_bf16.h>

#define N_NODES 100000
#define NB 784   // buckets of 128 nodes: 784*128 = 100352 >= N_NODES
#define NPAD 100352
#define BSH 7
#define BMASK 127
#define CAP 4096  // static per-bucket capacity (mean 2040 -> safe)
#define APAD 68   // padded LDS row stride (floats)

typedef float v2f __attribute__((ext_vector_type(2)));

__device__ inline void fma4(float a, const float4& w, float4& c) {
  c.x = fmaf(a, w.x, c.x);
  c.y = fmaf(a, w.y, c.y);
  c.z = fmaf(a, w.z, c.z);
  c.w = fmaf(a, w.w, c.w);
}
__device__ inline unsigned short f2bf(float f) {  // RNE f32->bf16
  unsigned u = __float_as_uint(f);
  u += 0x7fffu + ((u >> 16) & 1u);
  return (unsigned short)(u >> 16);
}
__device__ inline unsigned pack2bf(float a, float b) {
  return (unsigned)f2bf(a) | ((unsigned)f2bf(b) << 16);
}
__device__ inline float bflo(unsigned u) { return __uint_as_float(u << 16); }
__device__ inline float bfhi(unsigned u) { return __uint_as_float(u & 0xffff0000u); }
__device__ inline float bf2f(unsigned short u) {
  return __uint_as_float((unsigned)u << 16);
}

// ---------------------------------------------------------------------------
// bscatter (1024 threads, R9-proven line coalescing): packed edges
// (src<<7 | dst&127) into static bucket regions ep[b*CAP .. b*CAP+cnt_b).
// ---------------------------------------------------------------------------
__global__ __launch_bounds__(1024) void bscatter_k(const int* __restrict__ src,
                                                   const int* __restrict__ dst,
                                                   unsigned* __restrict__ bcur,
                                                   unsigned* __restrict__ ep,
                                                   int E) {
  __shared__ unsigned lh[NB];
  __shared__ unsigned lbase[NB];
  for (int i = threadIdx.x; i < NB; i += 1024) lh[i] = 0;
  __syncthreads();
  const int base = blockIdx.x * 16384;
  unsigned short rank[16];
  unsigned short bb[16];
#pragma unroll
  for (int it = 0; it < 16; ++it) {
    int e = base + it * 1024 + threadIdx.x;
    if (e < E) {
      unsigned b = ((unsigned)dst[e]) >> BSH;
      bb[it] = (unsigned short)b;
      rank[it] = (unsigned short)atomicAdd(&lh[b], 1u);
    }
  }
  __syncthreads();
  for (int i = threadIdx.x; i < NB; i += 1024)
    lbase[i] = lh[i] ? atomicAdd(&bcur[i], lh[i]) : 0u;
  __syncthreads();
#pragma unroll
  for (int it = 0; it < 16; ++it) {
    int e = base + it * 1024 + threadIdx.x;
    if (e < E) {
      unsigned b = bb[it];
      ep[(size_t)b * CAP + lbase[b] + rank[it]] =
          (((unsigned)src[e]) << BSH) | (((unsigned)dst[e]) & BMASK);
    }
  }
}

// ---------------------------------------------------------------------------
// Fused: blocks [0,GB1) = layer-1 dual-GEMM (xn bf16 + xs bf16);
// blocks [GB1,GB1+NB) = per-bucket counting sort (independent; overlaps).
// ---------------------------------------------------------------------------
#define GB1 1563  // ceil(100000/64)

__global__ __launch_bounds__(256) void fused1_k(
    const float* __restrict__ x, const float* __restrict__ W1n,
    const float* __restrict__ W1s, const float* __restrict__ b1,
    unsigned short* __restrict__ xnb, unsigned short* __restrict__ xsb,
    const unsigned* __restrict__ ep, const unsigned* __restrict__ bcur,
    int* __restrict__ ssrc, uint2* __restrict__ rows2, int M) {
  __shared__ __align__(16) float smem[12544];  // 50176 B
  const int tid = threadIdx.x;

  if (blockIdx.x >= GB1) {
    // ---------------- bsort body: bucket b ----------------
    const int b = blockIdx.x - GB1;
    unsigned* cnt = (unsigned*)smem;
    unsigned* sc = cnt + 128;
    const unsigned cntb = bcur[b];
    const unsigned beg = (unsigned)(b * CAP);
    if (tid < 128) cnt[tid] = 0;
    __syncthreads();
    for (unsigned j = tid; j < cntb; j += 256)
      atomicAdd(&cnt[ep[(size_t)beg + j] & BMASK], 1u);
    __syncthreads();
    unsigned v = (tid < 128) ? cnt[tid] : 0u;
    if (tid < 128) sc[tid] = v;
    __syncthreads();
    for (int off = 1; off < 128; off <<= 1) {
      unsigned t = (tid < 128 && tid >= off) ? sc[tid - off] : 0u;
      __syncthreads();
      if (tid < 128) sc[tid] += t;
      __syncthreads();
    }
    if (tid < 128) {
      unsigned ex = sc[tid] - v;
      rows2[b * 128 + tid] = make_uint2(beg + ex, beg + ex + v);
      cnt[tid] = ex;
    }
    __syncthreads();
    for (unsigned j = tid; j < cntb; j += 256) {
      unsigned p = ep[(size_t)beg + j];
      unsigned r = atomicAdd(&cnt[p & BMASK], 1u);
      ssrc[(size_t)beg + r] = (int)(p >> BSH);
    }
    return;
  }

  // ---------------- gemm1 body ----------------
  float* Wn = smem;
  float* Ws = smem + 4096;
  float* Ax = smem + 8192;  // 64*APAD
  const int row0 = blockIdx.x * 64;

  for (int i = tid; i < 1024; i += 256) {
    ((float4*)Wn)[i] = ((const float4*)W1n)[i];
    ((float4*)Ws)[i] = ((const float4*)W1s)[i];
  }
  for (int i = tid; i < 1024; i += 256) {
    int r = i >> 4, c = i & 15;
    long long gr = row0 + r;
    if (gr >= M) gr = M - 1;
    float4 v = ((const float4*)(x + gr * 64))[c];
    *(float4*)&Ax[r * APAD + 4 * c] = v;
  }
  __syncthreads();

  const int tx = tid & 15;
  const int ty = tid >> 4;
  const int arow = ty * 4;

  float4 an[4], as[4];
#pragma unroll
  for (int r = 0; r < 4; ++r) {
    an[r] = make_float4(0.f, 0.f, 0.f, 0.f);
    as[r] = make_float4(0.f, 0.f, 0.f, 0.f);
  }

#pragma unroll 1
  for (int k4 = 0; k4 < 16; ++k4) {
    float4 wn0 = *(const float4*)&Wn[(4 * k4 + 0) * 64 + 4 * tx];
    float4 wn1 = *(const float4*)&Wn[(4 * k4 + 1) * 64 + 4 * tx];
    float4 wn2 = *(const float4*)&Wn[(4 * k4 + 2) * 64 + 4 * tx];
    float4 wn3 = *(const float4*)&Wn[(4 * k4 + 3) * 64 + 4 * tx];
    float4 ws0 = *(const float4*)&Ws[(4 * k4 + 0) * 64 + 4 * tx];
    float4 ws1 = *(const float4*)&Ws[(4 * k4 + 1) * 64 + 4 * tx];
    float4 ws2 = *(const float4*)&Ws[(4 * k4 + 2) * 64 + 4 * tx];
    float4 ws3 = *(const float4*)&Ws[(4 * k4 + 3) * 64 + 4 * tx];
#pragma unroll
    for (int r = 0; r < 4; ++r) {
      float4 a = *(const float4*)&Ax[(arow + r) * APAD + 4 * k4];
      fma4(a.x, wn0, an[r]);
      fma4(a.y, wn1, an[r]);
      fma4(a.z, wn2, an[r]);
      fma4(a.w, wn3, an[r]);
      fma4(a.x, ws0, as[r]);
      fma4(a.y, ws1, as[r]);
      fma4(a.z, ws2, as[r]);
      fma4(a.w, ws3, as[r]);
    }
  }

  const float4 bv = *(const float4*)&b1[4 * tx];
#pragma unroll
  for (int r = 0; r < 4; ++r) {
    int row = row0 + arow + r;
    if (row < M) {
      ushort4 ps;
      ps.x = f2bf(as[r].x + bv.x);
      ps.y = f2bf(as[r].y + bv.y);
      ps.z = f2bf(as[r].z + bv.z);
      ps.w = f2bf(as[r].w + bv.w);
      *(ushort4*)&xsb[(long long)row * 64 + 4 * tx] = ps;
      ushort4 p;
      p.x = f2bf(an[r].x);
      p.y = f2bf(an[r].y);
      p.z = f2bf(an[r].z);
      p.w = f2bf(an[r].w);
      *(ushort4*)&xnb[(long long)row * 64 + 4 * tx] = p;
    }
  }
}

// ---------------------------------------------------------------------------
// gather1: mean1[node][:] = mean_j xnb[ssrc[j]][:]  -> bf16.
// P=8 lanes/node, uint4 loads, groups of 8 in flight.
// ---------------------------------------------------------------------------
__global__ __launch_bounds__(256) void gather1_k(
    const uint4* __restrict__ valb4, const int* __restrict__ ssrc,
    const uint2* __restrict__ rows2, uint4* __restrict__ meanb, int N) {
  constexpr int P = 8;
  const int node = blockIdx.x * (256 / P) + threadIdx.x / P;
  const int p = threadIdx.x & (P - 1);
  if (node >= N) return;
  const uint2 be = rows2[node];
  const unsigned beg = be.x, end = be.y;

  float acc[8];
#pragma unroll
  for (int q = 0; q < 8; ++q) acc[q] = 0.f;

  unsigned j = beg;
  for (; j + 8 <= end; j += 8) {
    int sn[8];
#pragma unroll
    for (int i = 0; i < 8; ++i) sn[i] = ssrc[j + i];
    uint4 u[8];
#pragma unroll
    for (int i = 0; i < 8; ++i) u[i] = valb4[(size_t)sn[i] * P + p];
#pragma unroll
    for (int i = 0; i < 8; ++i) {
      acc[0] += bflo(u[i].x);
      acc[1] += bfhi(u[i].x);
      acc[2] += bflo(u[i].y);
      acc[3] += bfhi(u[i].y);
      acc[4] += bflo(u[i].z);
      acc[5] += bfhi(u[i].z);
      acc[6] += bflo(u[i].w);
      acc[7] += bfhi(u[i].w);
    }
  }
  if (j < end) {
    const unsigned last = end - 1;
    int sn[8];
#pragma unroll
    for (int i = 0; i < 8; ++i) {
      unsigned jj = j + i;
      sn[i] = ssrc[jj < last ? jj : last];
    }
    uint4 u[8];
#pragma unroll
    for (int i = 0; i < 8; ++i) u[i] = valb4[(size_t)sn[i] * P + p];
#pragma unroll
    for (int i = 0; i < 8; ++i) {
      bool ok = (j + i) < end;
      acc[0] += ok ? bflo(u[i].x) : 0.f;
      acc[1] += ok ? bfhi(u[i].x) : 0.f;
      acc[2] += ok ? bflo(u[i].y) : 0.f;
      acc[3] += ok ? bfhi(u[i].y) : 0.f;
      acc[4] += ok ? bflo(u[i].z) : 0.f;
      acc[5] += ok ? bfhi(u[i].z) : 0.f;
      acc[6] += ok ? bflo(u[i].w) : 0.f;
      acc[7] += ok ? bfhi(u[i].w) : 0.f;
    }
  }

  const unsigned dg = end - beg;
  const float inv = dg ? 1.f / (float)dg : 0.f;
  uint4 pk;
  pk.x = pack2bf(acc[0] * inv, acc[1] * inv);
  pk.y = pack2bf(acc[2] * inv, acc[3] * inv);
  pk.z = pack2bf(acc[4] * inv, acc[5] * inv);
  pk.w = pack2bf(acc[6] * inv, acc[7] * inv);
  meanb[(size_t)node * P + p] = pk;
}

// ---------------------------------------------------------------------------
// Layer-2 dual-GEMM: stages Ah = relu(mean1(bf16) + xs(bf16)) in LDS,
// then hn = Ah@W2n (fp8 e4m3 out -> L2-resident gather table),
//      hs = Ah@W2s + b2 (f32).
// ---------------------------------------------------------------------------
__global__ __launch_bounds__(256) void gemm2_k(
    const unsigned short* __restrict__ mean1,
    const unsigned short* __restrict__ xsb, const float* __restrict__ W2n,
    const float* __restrict__ W2s, const float* __restrict__ b2,
    unsigned* __restrict__ hnb8, float* __restrict__ hs, int M) {
  __shared__ float Wn[64 * 32];
  __shared__ float Ws[64 * 32];
  __shared__ float Ah[128 * APAD];
  const int tid = threadIdx.x;
  const int row0 = blockIdx.x * 128;

  for (int i = tid; i < 512; i += 256) {
    ((float4*)Wn)[i] = ((const float4*)W2n)[i];
    ((float4*)Ws)[i] = ((const float4*)W2s)[i];
  }
  for (int i = tid; i < 2048; i += 256) {
    int r = i >> 4, c = i & 15;
    long long gr = row0 + r;
    if (gr >= M) gr = M - 1;
    ushort4 sv = ((const ushort4*)(xsb + gr * 64))[c];
    ushort4 mv = ((const ushort4*)(mean1 + gr * 64))[c];
    float4 v;
    v.x = fmaxf(bf2f(mv.x) + bf2f(sv.x), 0.f);
    v.y = fmaxf(bf2f(mv.y) + bf2f(sv.y), 0.f);
    v.z = fmaxf(bf2f(mv.z) + bf2f(sv.z), 0.f);
    v.w = fmaxf(bf2f(mv.w) + bf2f(sv.w), 0.f);
    *(float4*)&Ah[r * APAD + 4 * c] = v;
  }
  __syncthreads();

  const int tx = tid & 7;
  const int ty = tid >> 3;
  const int arow = ty * 4;

  float4 an[4], as[4];
#pragma unroll
  for (int r = 0; r < 4; ++r) {
    an[r] = make_float4(0.f, 0.f, 0.f, 0.f);
    as[r] = make_float4(0.f, 0.f, 0.f, 0.f);
  }

#pragma unroll 1
  for (int k4 = 0; k4 < 16; ++k4) {
    float4 wn0 = *(const float4*)&Wn[(4 * k4 + 0) * 32 + 4 * tx];
    float4 wn1 = *(const float4*)&Wn[(4 * k4 + 1) * 32 + 4 * tx];
    float4 wn2 = *(const float4*)&Wn[(4 * k4 + 2) * 32 + 4 * tx];
    float4 wn3 = *(const float4*)&Wn[(4 * k4 + 3) * 32 + 4 * tx];
    float4 ws0 = *(const float4*)&Ws[(4 * k4 + 0) * 32 + 4 * tx];
    float4 ws1 = *(const float4*)&Ws[(4 * k4 + 1) * 32 + 4 * tx];
    float4 ws2 = *(const float4*)&Ws[(4 * k4 + 2) * 32 + 4 * tx];
    float4 ws3 = *(const float4*)&Ws[(4 * k4 + 3) * 32 + 4 * tx];
#pragma unroll
    for (int r = 0; r < 4; ++r) {
      float4 a = *(const float4*)&Ah[(arow + r) * APAD + 4 * k4];
      fma4(a.x, wn0, an[r]);
      fma4(a.y, wn1, an[r]);
      fma4(a.z, wn2, an[r]);
      fma4(a.w, wn3, an[r]);
      fma4(a.x, ws0, as[r]);
      fma4(a.y, ws1, as[r]);
      fma4(a.z, ws2, as[r]);
      fma4(a.w, ws3, as[r]);
    }
  }

  const float4 bv = *(const float4*)&b2[4 * tx];
#pragma unroll
  for (int r = 0; r < 4; ++r) {
    int row = row0 + arow + r;
    if (row < M) {
      float4 o;
      o.x = as[r].x + bv.x;
      o.y = as[r].y + bv.y;
      o.z = as[r].z + bv.z;
      o.w = as[r].w + bv.w;
      *(float4*)&hs[(long long)row * 32 + 4 * tx] = o;
      int pk = __builtin_amdgcn_cvt_pk_fp8_f32(an[r].x, an[r].y, 0, false);
      pk = __builtin_amdgcn_cvt_pk_fp8_f32(an[r].z, an[r].w, pk, true);
      hnb8[(size_t)row * 8 + tx] = (unsigned)pk;
    }
  }
}

// ---------------------------------------------------------------------------
// gather2: out[node][:] = mean_j fp8decode(hnb8[ssrc[j]][:]) + hs[node][:]
// Row = 32 fp8 = 32 B = 2 uint4; P=2 lanes/node (16 cols each), 128 nodes/blk.
// Table is 3.2 MB -> L2-resident -> random reads are L2 hits.
// ---------------------------------------------------------------------------
__global__ __launch_bounds__(256) void gather2_k(
    const uint4* __restrict__ valb4, const int* __restrict__ ssrc,
    const uint2* __restrict__ rows2, const float* __restrict__ base,
    float* __restrict__ out, int N) {
  constexpr int P = 2;
  const int node = blockIdx.x * 128 + threadIdx.x / P;
  const int p = threadIdx.x & 1;
  if (node >= N) return;
  const uint2 be = rows2[node];
  const unsigned beg = be.x, end = be.y;

  float acc[16];
#pragma unroll
  for (int q = 0; q < 16; ++q) acc[q] = 0.f;

  unsigned j = beg;
  for (; j + 8 <= end; j += 8) {
    int sn[8];
#pragma unroll
    for (int i = 0; i < 8; ++i) sn[i] = ssrc[j + i];
    uint4 u[8];
#pragma unroll
    for (int i = 0; i < 8; ++i) u[i] = valb4[(size_t)sn[i] * P + p];
#pragma unroll
    for (int i = 0; i < 8; ++i) {
      v2f f0 = __builtin_amdgcn_cvt_pk_f32_fp8((int)u[i].x, false);
      v2f f1 = __builtin_amdgcn_cvt_pk_f32_fp8((int)u[i].x, true);
      v2f f2 = __builtin_amdgcn_cvt_pk_f32_fp8((int)u[i].y, false);
      v2f f3 = __builtin_amdgcn_cvt_pk_f32_fp8((int)u[i].y, true);
      v2f f4 = __builtin_amdgcn_cvt_pk_f32_fp8((int)u[i].z, false);
      v2f f5 = __builtin_amdgcn_cvt_pk_f32_fp8((int)u[i].z, true);
      v2f f6 = __builtin_amdgcn_cvt_pk_f32_fp8((int)u[i].w, false);
      v2f f7 = __builtin_amdgcn_cvt_pk_f32_fp8((int)u[i].w, true);
      acc[0] += f0[0];  acc[1] += f0[1];
      acc[2] += f1[0];  acc[3] += f1[1];
      acc[4] += f2[0];  acc[5] += f2[1];
      acc[6] += f3[0];  acc[7] += f3[1];
      acc[8] += f4[0];  acc[9] += f4[1];
      acc[10] += f5[0]; acc[11] += f5[1];
      acc[12] += f6[0]; acc[13] += f6[1];
      acc[14] += f7[0]; acc[15] += f7[1];
    }
  }
  if (j < end) {
    const unsigned last = end - 1;
    int sn[8];
#pragma unroll
    for (int i = 0; i < 8; ++i) {
      unsigned jj = j + i;
      sn[i] = ssrc[jj < last ? jj : last];
    }
    uint4 u[8];
#pragma unroll
    for (int i = 0; i < 8; ++i) u[i] = valb4[(size_t)sn[i] * P + p];
#pragma unroll
    for (int i = 0; i < 8; ++i) {
      float w = ((j + i) < end) ? 1.f : 0.f;
      v2f f0 = __builtin_amdgcn_cvt_pk_f32_fp8((int)u[i].x, false);
      v2f f1 = __builtin_amdgcn_cvt_pk_f32_fp8((int)u[i].x, true);
      v2f f2 = __builtin_amdgcn_cvt_pk_f32_fp8((int)u[i].y, false);
      v2f f3 = __builtin_amdgcn_cvt_pk_f32_fp8((int)u[i].y, true);
      v2f f4 = __builtin_amdgcn_cvt_pk_f32_fp8((int)u[i].z, false);
      v2f f5 = __builtin_amdgcn_cvt_pk_f32_fp8((int)u[i].z, true);
      v2f f6 = __builtin_amdgcn_cvt_pk_f32_fp8((int)u[i].w, false);
      v2f f7 = __builtin_amdgcn_cvt_pk_f32_fp8((int)u[i].w, true);
      acc[0] = fmaf(w, f0[0], acc[0]);   acc[1] = fmaf(w, f0[1], acc[1]);
      acc[2] = fmaf(w, f1[0], acc[2]);   acc[3] = fmaf(w, f1[1], acc[3]);
      acc[4] = fmaf(w, f2[0], acc[4]);   acc[5] = fmaf(w, f2[1], acc[5]);
      acc[6] = fmaf(w, f3[0], acc[6]);   acc[7] = fmaf(w, f3[1], acc[7]);
      acc[8] = fmaf(w, f4[0], acc[8]);   acc[9] = fmaf(w, f4[1], acc[9]);
      acc[10] = fmaf(w, f5[0], acc[10]); acc[11] = fmaf(w, f5[1], acc[11]);
      acc[12] = fmaf(w, f6[0], acc[12]); acc[13] = fmaf(w, f6[1], acc[13]);
      acc[14] = fmaf(w, f7[0], acc[14]); acc[15] = fmaf(w, f7[1], acc[15]);
    }
  }

  const unsigned dg = end - beg;
  const float inv = dg ? 1.f / (float)dg : 0.f;
  const size_t o = (size_t)node * 32 + 16 * p;
#pragma unroll
  for (int q4 = 0; q4 < 4; ++q4) {
    float4 bv = *(const float4*)&base[o + 4 * q4];
    float4 ov;
    ov.x = acc[4 * q4 + 0] * inv + bv.x;
    ov.y = acc[4 * q4 + 1] * inv + bv.y;
    ov.z = acc[4 * q4 + 2] * inv + bv.z;
    ov.w = acc[4 * q4 + 3] * inv + bv.w;
    *(float4*)&out[o + 4 * q4] = ov;
  }
}

extern "C" void kernel_launch(void* const* d_in, const int* in_sizes, int n_in,
                              void* d_out, int out_size, void* d_ws,
                              size_t ws_size, hipStream_t stream) {
  const float* x   = (const float*)d_in[0];
  const int*   ei  = (const int*)d_in[1];  // [2, E]: row0 = src, row1 = dst
  const float* W1n = (const float*)d_in[2];
  const float* W1s = (const float*)d_in[3];
  const float* b1  = (const float*)d_in[4];
  const float* W2n = (const float*)d_in[5];
  const float* W2s = (const float*)d_in[6];
  const float* b2  = (const float*)d_in[7];
  float* out = (float*)d_out;

  const int E = in_sizes[1] / 2;  // 1,600,000
  const int M = N_NODES;
  const int* src = ei;
  const int* dst = ei + E;

  // Workspace layout (bytes):
  //   ep    @ 0           12,845,056  (NB*CAP u32; layer2: hnb8 fp8 Mx32 aliases)
  //   ssrc  @ 12,845,056  12,845,056
  //   rows2 @ 25,690,112     802,816
  //   bcur  @ 26,492,928       3,136
  //   xnb   @ 26,496,064  12,800,000  (bf16 M x 64)
  //   xsb   @ 39,296,064  12,800,000  (bf16 M x 64)
  //   mean1 @ 52,096,064  12,800,000  (bf16 M x 64)
  //   hs    @ 64,896,064  12,800,000  (f32 M x 32)
  char* wsb = (char*)d_ws;
  unsigned*       ep    = (unsigned*)(wsb);
  int*            ssrc  = (int*)(wsb + 12845056);
  uint2*          rows2 = (uint2*)(wsb + 25690112);
  unsigned*       bcur  = (unsigned*)(wsb + 26492928);
  unsigned short* xnb   = (unsigned short*)(wsb + 26496064);
  unsigned short* xsb   = (unsigned short*)(wsb + 39296064);
  unsigned short* mean1 = (unsigned short*)(wsb + 52096064);
  float*          hs    = (float*)(wsb + 64896064);
  unsigned*       hnb8  = (unsigned*)(wsb);  // aliases ep (dead after fused1)

  // 1) zero bucket cursors (3 KB)
  hipMemsetAsync(bcur, 0, NB * 4, stream);
  // 2) scatter edges into static bucket regions
  bscatter_k<<<(E + 16383) / 16384, 1024, 0, stream>>>(src, dst, bcur, ep, E);
  // 3) fused: layer-1 dual-GEMM (xn bf16, xs bf16) + per-bucket counting sort
  fused1_k<<<GB1 + NB, 256, 0, stream>>>(x, W1n, W1s, b1, xnb, xsb, ep, bcur,
                                         ssrc, rows2, M);
  // 4) mean1(bf16) = mean(xn[src])
  gather1_k<<<(M + 31) / 32, 256, 0, stream>>>((const uint4*)xnb, ssrc, rows2,
                                               (uint4*)mean1, M);
  // 5) gemm2 stages relu(mean1+xs); hn(fp8)/hs = Ah@{W2n,W2s}+b2
  gemm2_k<<<(M + 127) / 128, 256, 0, stream>>>(mean1, xsb, W2n, W2s, b2, hnb8,
                                               hs, M);
  // 6) out = mean(fp8(hn)[src]) + hs
  gather2_k<<<(M + 127) / 128, 256, 0, stream>>>((const uint4*)hnb8, ssrc,
                                                 rows2, hs, out, M);
}

// Round 13
// 209.980 us; speedup vs baseline: 1.1292x; 1.0956x over previous
//
#include <hip/hip_runtime.h>
#include <hip/hip_bf16.h>

#define N_NODES 100000
#define NB 784   // buckets of 128 nodes: 784*128 = 100352 >= N_NODES
#define NPAD 100352
#define BSH 7
#define BMASK 127
#define CAP 4096  // static per-bucket capacity (mean 2040 -> safe)
#define APAD 68   // padded LDS row stride (floats)

typedef float v2f __attribute__((ext_vector_type(2)));

__device__ inline void fma4(float a, const float4& w, float4& c) {
  c.x = fmaf(a, w.x, c.x);
  c.y = fmaf(a, w.y, c.y);
  c.z = fmaf(a, w.z, c.z);
  c.w = fmaf(a, w.w, c.w);
}
__device__ inline unsigned short f2bf(float f) {  // RNE f32->bf16
  unsigned u = __float_as_uint(f);
  u += 0x7fffu + ((u >> 16) & 1u);
  return (unsigned short)(u >> 16);
}
__device__ inline unsigned pack2bf(float a, float b) {
  return (unsigned)f2bf(a) | ((unsigned)f2bf(b) << 16);
}
__device__ inline float bf2f(unsigned short u) {
  return __uint_as_float((unsigned)u << 16);
}
__device__ inline unsigned packfp8x4(float a, float b, float c, float d) {
  int pk = __builtin_amdgcn_cvt_pk_fp8_f32(a, b, 0, false);
  pk = __builtin_amdgcn_cvt_pk_fp8_f32(c, d, pk, true);
  return (unsigned)pk;
}

// ---------------------------------------------------------------------------
// bscatter (1024 threads): packed edges (src<<7 | dst&127) into static bucket
// regions ep[b*CAP .. b*CAP+cnt_b). Block-private contiguous write runs.
// ---------------------------------------------------------------------------
__global__ __launch_bounds__(1024) void bscatter_k(const int* __restrict__ src,
                                                   const int* __restrict__ dst,
                                                   unsigned* __restrict__ bcur,
                                                   unsigned* __restrict__ ep,
                                                   int E) {
  __shared__ unsigned lh[NB];
  __shared__ unsigned lbase[NB];
  for (int i = threadIdx.x; i < NB; i += 1024) lh[i] = 0;
  __syncthreads();
  const int base = blockIdx.x * 16384;
  unsigned short rank[16];
  unsigned short bb[16];
#pragma unroll
  for (int it = 0; it < 16; ++it) {
    int e = base + it * 1024 + threadIdx.x;
    if (e < E) {
      unsigned b = ((unsigned)dst[e]) >> BSH;
      bb[it] = (unsigned short)b;
      rank[it] = (unsigned short)atomicAdd(&lh[b], 1u);
    }
  }
  __syncthreads();
  for (int i = threadIdx.x; i < NB; i += 1024)
    lbase[i] = lh[i] ? atomicAdd(&bcur[i], lh[i]) : 0u;
  __syncthreads();
#pragma unroll
  for (int it = 0; it < 16; ++it) {
    int e = base + it * 1024 + threadIdx.x;
    if (e < E) {
      unsigned b = bb[it];
      ep[(size_t)b * CAP + lbase[b] + rank[it]] =
          (((unsigned)src[e]) << BSH) | (((unsigned)dst[e]) & BMASK);
    }
  }
}

// ---------------------------------------------------------------------------
// Fused: blocks [0,GB1) = layer-1 dual-GEMM (xn fp8 + xs bf16);
// blocks [GB1,GB1+NB) = per-bucket counting sort (independent; overlaps).
// ---------------------------------------------------------------------------
#define GB1 1563  // ceil(100000/64)

__global__ __launch_bounds__(256) void fused1_k(
    const float* __restrict__ x, const float* __restrict__ W1n,
    const float* __restrict__ W1s, const float* __restrict__ b1,
    unsigned* __restrict__ xnb8, unsigned short* __restrict__ xsb,
    const unsigned* __restrict__ ep, const unsigned* __restrict__ bcur,
    int* __restrict__ ssrc, uint2* __restrict__ rows2, int M) {
  __shared__ __align__(16) float smem[12544];  // 50176 B
  const int tid = threadIdx.x;

  if (blockIdx.x >= GB1) {
    // ---------------- bsort body: bucket b ----------------
    const int b = blockIdx.x - GB1;
    unsigned* cnt = (unsigned*)smem;
    unsigned* sc = cnt + 128;
    const unsigned cntb = bcur[b];
    const unsigned beg = (unsigned)(b * CAP);
    if (tid < 128) cnt[tid] = 0;
    __syncthreads();
    for (unsigned j = tid; j < cntb; j += 256)
      atomicAdd(&cnt[ep[(size_t)beg + j] & BMASK], 1u);
    __syncthreads();
    unsigned v = (tid < 128) ? cnt[tid] : 0u;
    if (tid < 128) sc[tid] = v;
    __syncthreads();
    for (int off = 1; off < 128; off <<= 1) {
      unsigned t = (tid < 128 && tid >= off) ? sc[tid - off] : 0u;
      __syncthreads();
      if (tid < 128) sc[tid] += t;
      __syncthreads();
    }
    if (tid < 128) {
      unsigned ex = sc[tid] - v;
      rows2[b * 128 + tid] = make_uint2(beg + ex, beg + ex + v);
      cnt[tid] = ex;
    }
    __syncthreads();
    for (unsigned j = tid; j < cntb; j += 256) {
      unsigned p = ep[(size_t)beg + j];
      unsigned r = atomicAdd(&cnt[p & BMASK], 1u);
      ssrc[(size_t)beg + r] = (int)(p >> BSH);
    }
    return;
  }

  // ---------------- gemm1 body ----------------
  float* Wn = smem;
  float* Ws = smem + 4096;
  float* Ax = smem + 8192;  // 64*APAD
  const int row0 = blockIdx.x * 64;

  for (int i = tid; i < 1024; i += 256) {
    ((float4*)Wn)[i] = ((const float4*)W1n)[i];
    ((float4*)Ws)[i] = ((const float4*)W1s)[i];
  }
  for (int i = tid; i < 1024; i += 256) {
    int r = i >> 4, c = i & 15;
    long long gr = row0 + r;
    if (gr >= M) gr = M - 1;
    float4 v = ((const float4*)(x + gr * 64))[c];
    *(float4*)&Ax[r * APAD + 4 * c] = v;
  }
  __syncthreads();

  const int tx = tid & 15;
  const int ty = tid >> 4;
  const int arow = ty * 4;

  float4 an[4], as[4];
#pragma unroll
  for (int r = 0; r < 4; ++r) {
    an[r] = make_float4(0.f, 0.f, 0.f, 0.f);
    as[r] = make_float4(0.f, 0.f, 0.f, 0.f);
  }

#pragma unroll 1
  for (int k4 = 0; k4 < 16; ++k4) {
    float4 wn0 = *(const float4*)&Wn[(4 * k4 + 0) * 64 + 4 * tx];
    float4 wn1 = *(const float4*)&Wn[(4 * k4 + 1) * 64 + 4 * tx];
    float4 wn2 = *(const float4*)&Wn[(4 * k4 + 2) * 64 + 4 * tx];
    float4 wn3 = *(const float4*)&Wn[(4 * k4 + 3) * 64 + 4 * tx];
    float4 ws0 = *(const float4*)&Ws[(4 * k4 + 0) * 64 + 4 * tx];
    float4 ws1 = *(const float4*)&Ws[(4 * k4 + 1) * 64 + 4 * tx];
    float4 ws2 = *(const float4*)&Ws[(4 * k4 + 2) * 64 + 4 * tx];
    float4 ws3 = *(const float4*)&Ws[(4 * k4 + 3) * 64 + 4 * tx];
#pragma unroll
    for (int r = 0; r < 4; ++r) {
      float4 a = *(const float4*)&Ax[(arow + r) * APAD + 4 * k4];
      fma4(a.x, wn0, an[r]);
      fma4(a.y, wn1, an[r]);
      fma4(a.z, wn2, an[r]);
      fma4(a.w, wn3, an[r]);
      fma4(a.x, ws0, as[r]);
      fma4(a.y, ws1, as[r]);
      fma4(a.z, ws2, as[r]);
      fma4(a.w, ws3, as[r]);
    }
  }

  const float4 bv = *(const float4*)&b1[4 * tx];
#pragma unroll
  for (int r = 0; r < 4; ++r) {
    int row = row0 + arow + r;
    if (row < M) {
      ushort4 ps;
      ps.x = f2bf(as[r].x + bv.x);
      ps.y = f2bf(as[r].y + bv.y);
      ps.z = f2bf(as[r].z + bv.z);
      ps.w = f2bf(as[r].w + bv.w);
      *(ushort4*)&xsb[(long long)row * 64 + 4 * tx] = ps;
      xnb8[(size_t)row * 16 + tx] =
          packfp8x4(an[r].x, an[r].y, an[r].z, an[r].w);
    }
  }
}

// ---------------------------------------------------------------------------
// gather1: mean1[node][:] = mean_j fp8decode(xnb8[ssrc[j]][:]) -> bf16.
// Row = 64 fp8 = 64 B = ONE cache line; P=4 lanes/node (16 cols each).
// Groups of 8 uint4 loads in flight; clamped/predicated tail group.
// ---------------------------------------------------------------------------
__global__ __launch_bounds__(256) void gather1_k(
    const uint4* __restrict__ valb4, const int* __restrict__ ssrc,
    const uint2* __restrict__ rows2, uint4* __restrict__ meanb, int N) {
  constexpr int P = 4;
  const int node = blockIdx.x * 64 + threadIdx.x / P;
  const int p = threadIdx.x & 3;
  if (node >= N) return;
  const uint2 be = rows2[node];
  const unsigned beg = be.x, end = be.y;

  float acc[16];
#pragma unroll
  for (int q = 0; q < 16; ++q) acc[q] = 0.f;

  unsigned j = beg;
  for (; j + 8 <= end; j += 8) {
    int sn[8];
#pragma unroll
    for (int i = 0; i < 8; ++i) sn[i] = ssrc[j + i];
    uint4 u[8];
#pragma unroll
    for (int i = 0; i < 8; ++i) u[i] = valb4[(size_t)sn[i] * P + p];
#pragma unroll
    for (int i = 0; i < 8; ++i) {
      v2f f0 = __builtin_amdgcn_cvt_pk_f32_fp8((int)u[i].x, false);
      v2f f1 = __builtin_amdgcn_cvt_pk_f32_fp8((int)u[i].x, true);
      v2f f2 = __builtin_amdgcn_cvt_pk_f32_fp8((int)u[i].y, false);
      v2f f3 = __builtin_amdgcn_cvt_pk_f32_fp8((int)u[i].y, true);
      v2f f4 = __builtin_amdgcn_cvt_pk_f32_fp8((int)u[i].z, false);
      v2f f5 = __builtin_amdgcn_cvt_pk_f32_fp8((int)u[i].z, true);
      v2f f6 = __builtin_amdgcn_cvt_pk_f32_fp8((int)u[i].w, false);
      v2f f7 = __builtin_amdgcn_cvt_pk_f32_fp8((int)u[i].w, true);
      acc[0] += f0[0];  acc[1] += f0[1];
      acc[2] += f1[0];  acc[3] += f1[1];
      acc[4] += f2[0];  acc[5] += f2[1];
      acc[6] += f3[0];  acc[7] += f3[1];
      acc[8] += f4[0];  acc[9] += f4[1];
      acc[10] += f5[0]; acc[11] += f5[1];
      acc[12] += f6[0]; acc[13] += f6[1];
      acc[14] += f7[0]; acc[15] += f7[1];
    }
  }
  if (j < end) {
    const unsigned last = end - 1;
    int sn[8];
#pragma unroll
    for (int i = 0; i < 8; ++i) {
      unsigned jj = j + i;
      sn[i] = ssrc[jj < last ? jj : last];
    }
    uint4 u[8];
#pragma unroll
    for (int i = 0; i < 8; ++i) u[i] = valb4[(size_t)sn[i] * P + p];
#pragma unroll
    for (int i = 0; i < 8; ++i) {
      float w = ((j + i) < end) ? 1.f : 0.f;
      v2f f0 = __builtin_amdgcn_cvt_pk_f32_fp8((int)u[i].x, false);
      v2f f1 = __builtin_amdgcn_cvt_pk_f32_fp8((int)u[i].x, true);
      v2f f2 = __builtin_amdgcn_cvt_pk_f32_fp8((int)u[i].y, false);
      v2f f3 = __builtin_amdgcn_cvt_pk_f32_fp8((int)u[i].y, true);
      v2f f4 = __builtin_amdgcn_cvt_pk_f32_fp8((int)u[i].z, false);
      v2f f5 = __builtin_amdgcn_cvt_pk_f32_fp8((int)u[i].z, true);
      v2f f6 = __builtin_amdgcn_cvt_pk_f32_fp8((int)u[i].w, false);
      v2f f7 = __builtin_amdgcn_cvt_pk_f32_fp8((int)u[i].w, true);
      acc[0] = fmaf(w, f0[0], acc[0]);   acc[1] = fmaf(w, f0[1], acc[1]);
      acc[2] = fmaf(w, f1[0], acc[2]);   acc[3] = fmaf(w, f1[1], acc[3]);
      acc[4] = fmaf(w, f2[0], acc[4]);   acc[5] = fmaf(w, f2[1], acc[5]);
      acc[6] = fmaf(w, f3[0], acc[6]);   acc[7] = fmaf(w, f3[1], acc[7]);
      acc[8] = fmaf(w, f4[0], acc[8]);   acc[9] = fmaf(w, f4[1], acc[9]);
      acc[10] = fmaf(w, f5[0], acc[10]); acc[11] = fmaf(w, f5[1], acc[11]);
      acc[12] = fmaf(w, f6[0], acc[12]); acc[13] = fmaf(w, f6[1], acc[13]);
      acc[14] = fmaf(w, f7[0], acc[14]); acc[15] = fmaf(w, f7[1], acc[15]);
    }
  }

  const unsigned dg = end - beg;
  const float inv = dg ? 1.f / (float)dg : 0.f;
  uint4 pk0, pk1;
  pk0.x = pack2bf(acc[0] * inv, acc[1] * inv);
  pk0.y = pack2bf(acc[2] * inv, acc[3] * inv);
  pk0.z = pack2bf(acc[4] * inv, acc[5] * inv);
  pk0.w = pack2bf(acc[6] * inv, acc[7] * inv);
  pk1.x = pack2bf(acc[8] * inv, acc[9] * inv);
  pk1.y = pack2bf(acc[10] * inv, acc[11] * inv);
  pk1.z = pack2bf(acc[12] * inv, acc[13] * inv);
  pk1.w = pack2bf(acc[14] * inv, acc[15] * inv);
  meanb[(size_t)node * 8 + 2 * p] = pk0;
  meanb[(size_t)node * 8 + 2 * p + 1] = pk1;
}

// ---------------------------------------------------------------------------
// Layer-2 dual-GEMM: stages Ah = relu(mean1(bf16) + xs(bf16)) in LDS,
// then hn = Ah@W2n (fp8 e4m3 out -> L2-resident gather table),
//      hs = Ah@W2s + b2 (f32).
// ---------------------------------------------------------------------------
__global__ __launch_bounds__(256) void gemm2_k(
    const unsigned short* __restrict__ mean1,
    const unsigned short* __restrict__ xsb, const float* __restrict__ W2n,
    const float* __restrict__ W2s, const float* __restrict__ b2,
    unsigned* __restrict__ hnb8, float* __restrict__ hs, int M) {
  __shared__ float Wn[64 * 32];
  __shared__ float Ws[64 * 32];
  __shared__ float Ah[128 * APAD];
  const int tid = threadIdx.x;
  const int row0 = blockIdx.x * 128;

  for (int i = tid; i < 512; i += 256) {
    ((float4*)Wn)[i] = ((const float4*)W2n)[i];
    ((float4*)Ws)[i] = ((const float4*)W2s)[i];
  }
  for (int i = tid; i < 2048; i += 256) {
    int r = i >> 4, c = i & 15;
    long long gr = row0 + r;
    if (gr >= M) gr = M - 1;
    ushort4 sv = ((const ushort4*)(xsb + gr * 64))[c];
    ushort4 mv = ((const ushort4*)(mean1 + gr * 64))[c];
    float4 v;
    v.x = fmaxf(bf2f(mv.x) + bf2f(sv.x), 0.f);
    v.y = fmaxf(bf2f(mv.y) + bf2f(sv.y), 0.f);
    v.z = fmaxf(bf2f(mv.z) + bf2f(sv.z), 0.f);
    v.w = fmaxf(bf2f(mv.w) + bf2f(sv.w), 0.f);
    *(float4*)&Ah[r * APAD + 4 * c] = v;
  }
  __syncthreads();

  const int tx = tid & 7;
  const int ty = tid >> 3;
  const int arow = ty * 4;

  float4 an[4], as[4];
#pragma unroll
  for (int r = 0; r < 4; ++r) {
    an[r] = make_float4(0.f, 0.f, 0.f, 0.f);
    as[r] = make_float4(0.f, 0.f, 0.f, 0.f);
  }

#pragma unroll 1
  for (int k4 = 0; k4 < 16; ++k4) {
    float4 wn0 = *(const float4*)&Wn[(4 * k4 + 0) * 32 + 4 * tx];
    float4 wn1 = *(const float4*)&Wn[(4 * k4 + 1) * 32 + 4 * tx];
    float4 wn2 = *(const float4*)&Wn[(4 * k4 + 2) * 32 + 4 * tx];
    float4 wn3 = *(const float4*)&Wn[(4 * k4 + 3) * 32 + 4 * tx];
    float4 ws0 = *(const float4*)&Ws[(4 * k4 + 0) * 32 + 4 * tx];
    float4 ws1 = *(const float4*)&Ws[(4 * k4 + 1) * 32 + 4 * tx];
    float4 ws2 = *(const float4*)&Ws[(4 * k4 + 2) * 32 + 4 * tx];
    float4 ws3 = *(const float4*)&Ws[(4 * k4 + 3) * 32 + 4 * tx];
#pragma unroll
    for (int r = 0; r < 4; ++r) {
      float4 a = *(const float4*)&Ah[(arow + r) * APAD + 4 * k4];
      fma4(a.x, wn0, an[r]);
      fma4(a.y, wn1, an[r]);
      fma4(a.z, wn2, an[r]);
      fma4(a.w, wn3, an[r]);
      fma4(a.x, ws0, as[r]);
      fma4(a.y, ws1, as[r]);
      fma4(a.z, ws2, as[r]);
      fma4(a.w, ws3, as[r]);
    }
  }

  const float4 bv = *(const float4*)&b2[4 * tx];
#pragma unroll
  for (int r = 0; r < 4; ++r) {
    int row = row0 + arow + r;
    if (row < M) {
      float4 o;
      o.x = as[r].x + bv.x;
      o.y = as[r].y + bv.y;
      o.z = as[r].z + bv.z;
      o.w = as[r].w + bv.w;
      *(float4*)&hs[(long long)row * 32 + 4 * tx] = o;
      hnb8[(size_t)row * 8 + tx] =
          packfp8x4(an[r].x, an[r].y, an[r].z, an[r].w);
    }
  }
}

// ---------------------------------------------------------------------------
// gather2: out[node][:] = mean_j fp8decode(hnb8[ssrc[j]][:]) + hs[node][:]
// Row = 32 fp8 = 32 B; table 3.2 MB -> L2-resident. P=2 lanes/node.
// ---------------------------------------------------------------------------
__global__ __launch_bounds__(256) void gather2_k(
    const uint4* __restrict__ valb4, const int* __restrict__ ssrc,
    const uint2* __restrict__ rows2, const float* __restrict__ base,
    float* __restrict__ out, int N) {
  constexpr int P = 2;
  const int node = blockIdx.x * 128 + threadIdx.x / P;
  const int p = threadIdx.x & 1;
  if (node >= N) return;
  const uint2 be = rows2[node];
  const unsigned beg = be.x, end = be.y;

  float acc[16];
#pragma unroll
  for (int q = 0; q < 16; ++q) acc[q] = 0.f;

  unsigned j = beg;
  for (; j + 8 <= end; j += 8) {
    int sn[8];
#pragma unroll
    for (int i = 0; i < 8; ++i) sn[i] = ssrc[j + i];
    uint4 u[8];
#pragma unroll
    for (int i = 0; i < 8; ++i) u[i] = valb4[(size_t)sn[i] * P + p];
#pragma unroll
    for (int i = 0; i < 8; ++i) {
      v2f f0 = __builtin_amdgcn_cvt_pk_f32_fp8((int)u[i].x, false);
      v2f f1 = __builtin_amdgcn_cvt_pk_f32_fp8((int)u[i].x, true);
      v2f f2 = __builtin_amdgcn_cvt_pk_f32_fp8((int)u[i].y, false);
      v2f f3 = __builtin_amdgcn_cvt_pk_f32_fp8((int)u[i].y, true);
      v2f f4 = __builtin_amdgcn_cvt_pk_f32_fp8((int)u[i].z, false);
      v2f f5 = __builtin_amdgcn_cvt_pk_f32_fp8((int)u[i].z, true);
      v2f f6 = __builtin_amdgcn_cvt_pk_f32_fp8((int)u[i].w, false);
      v2f f7 = __builtin_amdgcn_cvt_pk_f32_fp8((int)u[i].w, true);
      acc[0] += f0[0];  acc[1] += f0[1];
      acc[2] += f1[0];  acc[3] += f1[1];
      acc[4] += f2[0];  acc[5] += f2[1];
      acc[6] += f3[0];  acc[7] += f3[1];
      acc[8] += f4[0];  acc[9] += f4[1];
      acc[10] += f5[0]; acc[11] += f5[1];
      acc[12] += f6[0]; acc[13] += f6[1];
      acc[14] += f7[0]; acc[15] += f7[1];
    }
  }
  if (j < end) {
    const unsigned last = end - 1;
    int sn[8];
#pragma unroll
    for (int i = 0; i < 8; ++i) {
      unsigned jj = j + i;
      sn[i] = ssrc[jj < last ? jj : last];
    }
    uint4 u[8];
#pragma unroll
    for (int i = 0; i < 8; ++i) u[i] = valb4[(size_t)sn[i] * P + p];
#pragma unroll
    for (int i = 0; i < 8; ++i) {
      float w = ((j + i) < end) ? 1.f : 0.f;
      v2f f0 = __builtin_amdgcn_cvt_pk_f32_fp8((int)u[i].x, false);
      v2f f1 = __builtin_amdgcn_cvt_pk_f32_fp8((int)u[i].x, true);
      v2f f2 = __builtin_amdgcn_cvt_pk_f32_fp8((int)u[i].y, false);
      v2f f3 = __builtin_amdgcn_cvt_pk_f32_fp8((int)u[i].y, true);
      v2f f4 = __builtin_amdgcn_cvt_pk_f32_fp8((int)u[i].z, false);
      v2f f5 = __builtin_amdgcn_cvt_pk_f32_fp8((int)u[i].z, true);
      v2f f6 = __builtin_amdgcn_cvt_pk_f32_fp8((int)u[i].w, false);
      v2f f7 = __builtin_amdgcn_cvt_pk_f32_fp8((int)u[i].w, true);
      acc[0] = fmaf(w, f0[0], acc[0]);   acc[1] = fmaf(w, f0[1], acc[1]);
      acc[2] = fmaf(w, f1[0], acc[2]);   acc[3] = fmaf(w, f1[1], acc[3]);
      acc[4] = fmaf(w, f2[0], acc[4]);   acc[5] = fmaf(w, f2[1], acc[5]);
      acc[6] = fmaf(w, f3[0], acc[6]);   acc[7] = fmaf(w, f3[1], acc[7]);
      acc[8] = fmaf(w, f4[0], acc[8]);   acc[9] = fmaf(w, f4[1], acc[9]);
      acc[10] = fmaf(w, f5[0], acc[10]); acc[11] = fmaf(w, f5[1], acc[11]);
      acc[12] = fmaf(w, f6[0], acc[12]); acc[13] = fmaf(w, f6[1], acc[13]);
      acc[14] = fmaf(w, f7[0], acc[14]); acc[15] = fmaf(w, f7[1], acc[15]);
    }
  }

  const unsigned dg = end - beg;
  const float inv = dg ? 1.f / (float)dg : 0.f;
  const size_t o = (size_t)node * 32 + 16 * p;
#pragma unroll
  for (int q4 = 0; q4 < 4; ++q4) {
    float4 bv = *(const float4*)&base[o + 4 * q4];
    float4 ov;
    ov.x = acc[4 * q4 + 0] * inv + bv.x;
    ov.y = acc[4 * q4 + 1] * inv + bv.y;
    ov.z = acc[4 * q4 + 2] * inv + bv.z;
    ov.w = acc[4 * q4 + 3] * inv + bv.w;
    *(float4*)&out[o + 4 * q4] = ov;
  }
}

extern "C" void kernel_launch(void* const* d_in, const int* in_sizes, int n_in,
                              void* d_out, int out_size, void* d_ws,
                              size_t ws_size, hipStream_t stream) {
  const float* x   = (const float*)d_in[0];
  const int*   ei  = (const int*)d_in[1];  // [2, E]: row0 = src, row1 = dst
  const float* W1n = (const float*)d_in[2];
  const float* W1s = (const float*)d_in[3];
  const float* b1  = (const float*)d_in[4];
  const float* W2n = (const float*)d_in[5];
  const float* W2s = (const float*)d_in[6];
  const float* b2  = (const float*)d_in[7];
  float* out = (float*)d_out;

  const int E = in_sizes[1] / 2;  // 1,600,000
  const int M = N_NODES;
  const int* src = ei;
  const int* dst = ei + E;

  // Workspace layout (bytes):
  //   ep    @ 0           12,845,056  (NB*CAP u32; layer2: hnb8 fp8 Mx32 aliases)
  //   ssrc  @ 12,845,056  12,845,056
  //   rows2 @ 25,690,112     802,816
  //   bcur  @ 26,492,928       3,136
  //   xnb8  @ 26,496,064   6,400,000  (fp8 M x 64)
  //   xsb   @ 32,896,064  12,800,000  (bf16 M x 64)
  //   mean1 @ 45,696,064  12,800,000  (bf16 M x 64)
  //   hs    @ 58,496,064  12,800,000  (f32 M x 32)
  char* wsb = (char*)d_ws;
  unsigned*       ep    = (unsigned*)(wsb);
  int*            ssrc  = (int*)(wsb + 12845056);
  uint2*          rows2 = (uint2*)(wsb + 25690112);
  unsigned*       bcur  = (unsigned*)(wsb + 26492928);
  unsigned*       xnb8  = (unsigned*)(wsb + 26496064);
  unsigned short* xsb   = (unsigned short*)(wsb + 32896064);
  unsigned short* mean1 = (unsigned short*)(wsb + 45696064);
  float*          hs    = (float*)(wsb + 58496064);
  unsigned*       hnb8  = (unsigned*)(wsb);  // aliases ep (dead after fused1)

  // 1) zero bucket cursors (3 KB)
  hipMemsetAsync(bcur, 0, NB * 4, stream);
  // 2) scatter edges into static bucket regions
  bscatter_k<<<(E + 16383) / 16384, 1024, 0, stream>>>(src, dst, bcur, ep, E);
  // 3) fused: layer-1 dual-GEMM (xn fp8, xs bf16) + per-bucket counting sort
  fused1_k<<<GB1 + NB, 256, 0, stream>>>(x, W1n, W1s, b1, xnb8, xsb, ep, bcur,
                                         ssrc, rows2, M);
  // 4) mean1(bf16) = mean(fp8(xn)[src])  -- 64 B rows, one line per edge
  gather1_k<<<(M + 63) / 64, 256, 0, stream>>>((const uint4*)xnb8, ssrc, rows2,
                                               (uint4*)mean1, M);
  // 5) gemm2 stages relu(mean1+xs); hn(fp8)/hs = Ah@{W2n,W2s}+b2
  gemm2_k<<<(M + 127) / 128, 256, 0, stream>>>(mean1, xsb, W2n, W2s, b2, hnb8,
                                               hs, M);
  // 6) out = mean(fp8(hn)[src]) + hs
  gather2_k<<<(M + 127) / 128, 256, 0, stream>>>((const uint4*)hnb8, ssrc,
                                                 rows2, hs, out, M);
}

// Round 14
// 204.548 us; speedup vs baseline: 1.1592x; 1.0266x over previous
//
#include <hip/hip_runtime.h>
#include <hip/hip_bf16.h>

#define N_NODES 100000
#define NB 784   // buckets of 128 nodes: 784*128 = 100352 >= N_NODES
#define NPAD 100352
#define BSH 7
#define BMASK 127
#define CAP 4096  // static per-bucket capacity (mean 2040 -> safe)
#define APAD 68   // padded LDS row stride (floats)

typedef float v2f __attribute__((ext_vector_type(2)));

__device__ inline void fma4(float a, const float4& w, float4& c) {
  c.x = fmaf(a, w.x, c.x);
  c.y = fmaf(a, w.y, c.y);
  c.z = fmaf(a, w.z, c.z);
  c.w = fmaf(a, w.w, c.w);
}
__device__ inline unsigned short f2bf(float f) {  // RNE f32->bf16
  unsigned u = __float_as_uint(f);
  u += 0x7fffu + ((u >> 16) & 1u);
  return (unsigned short)(u >> 16);
}
__device__ inline unsigned pack2bf(float a, float b) {
  return (unsigned)f2bf(a) | ((unsigned)f2bf(b) << 16);
}
__device__ inline float bf2f(unsigned short u) {
  return __uint_as_float((unsigned)u << 16);
}
__device__ inline unsigned packfp8x4(float a, float b, float c, float d) {
  int pk = __builtin_amdgcn_cvt_pk_fp8_f32(a, b, 0, false);
  pk = __builtin_amdgcn_cvt_pk_fp8_f32(c, d, pk, true);
  return (unsigned)pk;
}

// ---------------------------------------------------------------------------
// bscatter: 391 blocks x 512 threads x 8 edges (R13 fix: 98 blocks left 62%
// of CUs idle at 44 us; issue-bound work now spread over all 256 CUs).
// Packed edges (src<<7 | dst&127) into static bucket regions
// ep[b*CAP .. b*CAP+cnt_b); per-block LDS ranks -> block-private runs.
// ---------------------------------------------------------------------------
#define EPB 4096
__global__ __launch_bounds__(512) void bscatter_k(const int* __restrict__ src,
                                                  const int* __restrict__ dst,
                                                  unsigned* __restrict__ bcur,
                                                  unsigned* __restrict__ ep,
                                                  int E) {
  __shared__ unsigned lh[NB];
  __shared__ unsigned lbase[NB];
  for (int i = threadIdx.x; i < NB; i += 512) lh[i] = 0;
  __syncthreads();
  const int base = blockIdx.x * EPB;
  unsigned short rank[8];
  unsigned short bb[8];
#pragma unroll
  for (int it = 0; it < 8; ++it) {
    int e = base + it * 512 + threadIdx.x;
    if (e < E) {
      unsigned b = ((unsigned)dst[e]) >> BSH;
      bb[it] = (unsigned short)b;
      rank[it] = (unsigned short)atomicAdd(&lh[b], 1u);
    }
  }
  __syncthreads();
  for (int i = threadIdx.x; i < NB; i += 512)
    lbase[i] = lh[i] ? atomicAdd(&bcur[i], lh[i]) : 0u;
  __syncthreads();
#pragma unroll
  for (int it = 0; it < 8; ++it) {
    int e = base + it * 512 + threadIdx.x;
    if (e < E) {
      unsigned b = bb[it];
      ep[(size_t)b * CAP + lbase[b] + rank[it]] =
          (((unsigned)src[e]) << BSH) | (((unsigned)dst[e]) & BMASK);
    }
  }
}

// ---------------------------------------------------------------------------
// Fused: blocks [0,GB1) = layer-1 dual-GEMM (xn fp8 + xs bf16);
// blocks [GB1,GB1+NB) = per-bucket counting sort (independent; overlaps).
// ---------------------------------------------------------------------------
#define GB1 1563  // ceil(100000/64)

__global__ __launch_bounds__(256) void fused1_k(
    const float* __restrict__ x, const float* __restrict__ W1n,
    const float* __restrict__ W1s, const float* __restrict__ b1,
    unsigned* __restrict__ xnb8, unsigned short* __restrict__ xsb,
    const unsigned* __restrict__ ep, const unsigned* __restrict__ bcur,
    int* __restrict__ ssrc, uint2* __restrict__ rows2, int M) {
  __shared__ __align__(16) float smem[12544];  // 50176 B
  const int tid = threadIdx.x;

  if (blockIdx.x >= GB1) {
    // ---------------- bsort body: bucket b ----------------
    const int b = blockIdx.x - GB1;
    unsigned* cnt = (unsigned*)smem;
    unsigned* sc = cnt + 128;
    const unsigned cntb = bcur[b];
    const unsigned beg = (unsigned)(b * CAP);
    if (tid < 128) cnt[tid] = 0;
    __syncthreads();
    for (unsigned j = tid; j < cntb; j += 256)
      atomicAdd(&cnt[ep[(size_t)beg + j] & BMASK], 1u);
    __syncthreads();
    unsigned v = (tid < 128) ? cnt[tid] : 0u;
    if (tid < 128) sc[tid] = v;
    __syncthreads();
    for (int off = 1; off < 128; off <<= 1) {
      unsigned t = (tid < 128 && tid >= off) ? sc[tid - off] : 0u;
      __syncthreads();
      if (tid < 128) sc[tid] += t;
      __syncthreads();
    }
    if (tid < 128) {
      unsigned ex = sc[tid] - v;
      rows2[b * 128 + tid] = make_uint2(beg + ex, beg + ex + v);
      cnt[tid] = ex;
    }
    __syncthreads();
    for (unsigned j = tid; j < cntb; j += 256) {
      unsigned p = ep[(size_t)beg + j];
      unsigned r = atomicAdd(&cnt[p & BMASK], 1u);
      ssrc[(size_t)beg + r] = (int)(p >> BSH);
    }
    return;
  }

  // ---------------- gemm1 body ----------------
  float* Wn = smem;
  float* Ws = smem + 4096;
  float* Ax = smem + 8192;  // 64*APAD
  const int row0 = blockIdx.x * 64;

  for (int i = tid; i < 1024; i += 256) {
    ((float4*)Wn)[i] = ((const float4*)W1n)[i];
    ((float4*)Ws)[i] = ((const float4*)W1s)[i];
  }
  for (int i = tid; i < 1024; i += 256) {
    int r = i >> 4, c = i & 15;
    long long gr = row0 + r;
    if (gr >= M) gr = M - 1;
    float4 v = ((const float4*)(x + gr * 64))[c];
    *(float4*)&Ax[r * APAD + 4 * c] = v;
  }
  __syncthreads();

  const int tx = tid & 15;
  const int ty = tid >> 4;
  const int arow = ty * 4;

  float4 an[4], as[4];
#pragma unroll
  for (int r = 0; r < 4; ++r) {
    an[r] = make_float4(0.f, 0.f, 0.f, 0.f);
    as[r] = make_float4(0.f, 0.f, 0.f, 0.f);
  }

#pragma unroll 1
  for (int k4 = 0; k4 < 16; ++k4) {
    float4 wn0 = *(const float4*)&Wn[(4 * k4 + 0) * 64 + 4 * tx];
    float4 wn1 = *(const float4*)&Wn[(4 * k4 + 1) * 64 + 4 * tx];
    float4 wn2 = *(const float4*)&Wn[(4 * k4 + 2) * 64 + 4 * tx];
    float4 wn3 = *(const float4*)&Wn[(4 * k4 + 3) * 64 + 4 * tx];
    float4 ws0 = *(const float4*)&Ws[(4 * k4 + 0) * 64 + 4 * tx];
    float4 ws1 = *(const float4*)&Ws[(4 * k4 + 1) * 64 + 4 * tx];
    float4 ws2 = *(const float4*)&Ws[(4 * k4 + 2) * 64 + 4 * tx];
    float4 ws3 = *(const float4*)&Ws[(4 * k4 + 3) * 64 + 4 * tx];
#pragma unroll
    for (int r = 0; r < 4; ++r) {
      float4 a = *(const float4*)&Ax[(arow + r) * APAD + 4 * k4];
      fma4(a.x, wn0, an[r]);
      fma4(a.y, wn1, an[r]);
      fma4(a.z, wn2, an[r]);
      fma4(a.w, wn3, an[r]);
      fma4(a.x, ws0, as[r]);
      fma4(a.y, ws1, as[r]);
      fma4(a.z, ws2, as[r]);
      fma4(a.w, ws3, as[r]);
    }
  }

  const float4 bv = *(const float4*)&b1[4 * tx];
#pragma unroll
  for (int r = 0; r < 4; ++r) {
    int row = row0 + arow + r;
    if (row < M) {
      ushort4 ps;
      ps.x = f2bf(as[r].x + bv.x);
      ps.y = f2bf(as[r].y + bv.y);
      ps.z = f2bf(as[r].z + bv.z);
      ps.w = f2bf(as[r].w + bv.w);
      *(ushort4*)&xsb[(long long)row * 64 + 4 * tx] = ps;
      xnb8[(size_t)row * 16 + tx] =
          packfp8x4(an[r].x, an[r].y, an[r].z, an[r].w);
    }
  }
}

// ---------------------------------------------------------------------------
// gather1: mean1[node][:] = mean_j fp8decode(xnb8[ssrc[j]][:]) -> bf16.
// Row = 64 fp8 = 64 B = ONE cache line; P=4 lanes/node (16 cols each).
// ---------------------------------------------------------------------------
__global__ __launch_bounds__(256) void gather1_k(
    const uint4* __restrict__ valb4, const int* __restrict__ ssrc,
    const uint2* __restrict__ rows2, uint4* __restrict__ meanb, int N) {
  constexpr int P = 4;
  const int node = blockIdx.x * 64 + threadIdx.x / P;
  const int p = threadIdx.x & 3;
  if (node >= N) return;
  const uint2 be = rows2[node];
  const unsigned beg = be.x, end = be.y;

  float acc[16];
#pragma unroll
  for (int q = 0; q < 16; ++q) acc[q] = 0.f;

  unsigned j = beg;
  for (; j + 8 <= end; j += 8) {
    int sn[8];
#pragma unroll
    for (int i = 0; i < 8; ++i) sn[i] = ssrc[j + i];
    uint4 u[8];
#pragma unroll
    for (int i = 0; i < 8; ++i) u[i] = valb4[(size_t)sn[i] * P + p];
#pragma unroll
    for (int i = 0; i < 8; ++i) {
      v2f f0 = __builtin_amdgcn_cvt_pk_f32_fp8((int)u[i].x, false);
      v2f f1 = __builtin_amdgcn_cvt_pk_f32_fp8((int)u[i].x, true);
      v2f f2 = __builtin_amdgcn_cvt_pk_f32_fp8((int)u[i].y, false);
      v2f f3 = __builtin_amdgcn_cvt_pk_f32_fp8((int)u[i].y, true);
      v2f f4 = __builtin_amdgcn_cvt_pk_f32_fp8((int)u[i].z, false);
      v2f f5 = __builtin_amdgcn_cvt_pk_f32_fp8((int)u[i].z, true);
      v2f f6 = __builtin_amdgcn_cvt_pk_f32_fp8((int)u[i].w, false);
      v2f f7 = __builtin_amdgcn_cvt_pk_f32_fp8((int)u[i].w, true);
      acc[0] += f0[0];  acc[1] += f0[1];
      acc[2] += f1[0];  acc[3] += f1[1];
      acc[4] += f2[0];  acc[5] += f2[1];
      acc[6] += f3[0];  acc[7] += f3[1];
      acc[8] += f4[0];  acc[9] += f4[1];
      acc[10] += f5[0]; acc[11] += f5[1];
      acc[12] += f6[0]; acc[13] += f6[1];
      acc[14] += f7[0]; acc[15] += f7[1];
    }
  }
  if (j < end) {
    const unsigned last = end - 1;
    int sn[8];
#pragma unroll
    for (int i = 0; i < 8; ++i) {
      unsigned jj = j + i;
      sn[i] = ssrc[jj < last ? jj : last];
    }
    uint4 u[8];
#pragma unroll
    for (int i = 0; i < 8; ++i) u[i] = valb4[(size_t)sn[i] * P + p];
#pragma unroll
    for (int i = 0; i < 8; ++i) {
      float w = ((j + i) < end) ? 1.f : 0.f;
      v2f f0 = __builtin_amdgcn_cvt_pk_f32_fp8((int)u[i].x, false);
      v2f f1 = __builtin_amdgcn_cvt_pk_f32_fp8((int)u[i].x, true);
      v2f f2 = __builtin_amdgcn_cvt_pk_f32_fp8((int)u[i].y, false);
      v2f f3 = __builtin_amdgcn_cvt_pk_f32_fp8((int)u[i].y, true);
      v2f f4 = __builtin_amdgcn_cvt_pk_f32_fp8((int)u[i].z, false);
      v2f f5 = __builtin_amdgcn_cvt_pk_f32_fp8((int)u[i].z, true);
      v2f f6 = __builtin_amdgcn_cvt_pk_f32_fp8((int)u[i].w, false);
      v2f f7 = __builtin_amdgcn_cvt_pk_f32_fp8((int)u[i].w, true);
      acc[0] = fmaf(w, f0[0], acc[0]);   acc[1] = fmaf(w, f0[1], acc[1]);
      acc[2] = fmaf(w, f1[0], acc[2]);   acc[3] = fmaf(w, f1[1], acc[3]);
      acc[4] = fmaf(w, f2[0], acc[4]);   acc[5] = fmaf(w, f2[1], acc[5]);
      acc[6] = fmaf(w, f3[0], acc[6]);   acc[7] = fmaf(w, f3[1], acc[7]);
      acc[8] = fmaf(w, f4[0], acc[8]);   acc[9] = fmaf(w, f4[1], acc[9]);
      acc[10] = fmaf(w, f5[0], acc[10]); acc[11] = fmaf(w, f5[1], acc[11]);
      acc[12] = fmaf(w, f6[0], acc[12]); acc[13] = fmaf(w, f6[1], acc[13]);
      acc[14] = fmaf(w, f7[0], acc[14]); acc[15] = fmaf(w, f7[1], acc[15]);
    }
  }

  const unsigned dg = end - beg;
  const float inv = dg ? 1.f / (float)dg : 0.f;
  uint4 pk0, pk1;
  pk0.x = pack2bf(acc[0] * inv, acc[1] * inv);
  pk0.y = pack2bf(acc[2] * inv, acc[3] * inv);
  pk0.z = pack2bf(acc[4] * inv, acc[5] * inv);
  pk0.w = pack2bf(acc[6] * inv, acc[7] * inv);
  pk1.x = pack2bf(acc[8] * inv, acc[9] * inv);
  pk1.y = pack2bf(acc[10] * inv, acc[11] * inv);
  pk1.z = pack2bf(acc[12] * inv, acc[13] * inv);
  pk1.w = pack2bf(acc[14] * inv, acc[15] * inv);
  meanb[(size_t)node * 8 + 2 * p] = pk0;
  meanb[(size_t)node * 8 + 2 * p + 1] = pk1;
}

// ---------------------------------------------------------------------------
// Layer-2 dual-GEMM: stages Ah = relu(mean1(bf16) + xs(bf16)) in LDS,
// then hn = Ah@W2n (fp8 e4m3 out), hs = Ah@W2s + b2 (f32).
// ---------------------------------------------------------------------------
__global__ __launch_bounds__(256) void gemm2_k(
    const unsigned short* __restrict__ mean1,
    const unsigned short* __restrict__ xsb, const float* __restrict__ W2n,
    const float* __restrict__ W2s, const float* __restrict__ b2,
    unsigned* __restrict__ hnb8, float* __restrict__ hs, int M) {
  __shared__ float Wn[64 * 32];
  __shared__ float Ws[64 * 32];
  __shared__ float Ah[128 * APAD];
  const int tid = threadIdx.x;
  const int row0 = blockIdx.x * 128;

  for (int i = tid; i < 512; i += 256) {
    ((float4*)Wn)[i] = ((const float4*)W2n)[i];
    ((float4*)Ws)[i] = ((const float4*)W2s)[i];
  }
  for (int i = tid; i < 2048; i += 256) {
    int r = i >> 4, c = i & 15;
    long long gr = row0 + r;
    if (gr >= M) gr = M - 1;
    ushort4 sv = ((const ushort4*)(xsb + gr * 64))[c];
    ushort4 mv = ((const ushort4*)(mean1 + gr * 64))[c];
    float4 v;
    v.x = fmaxf(bf2f(mv.x) + bf2f(sv.x), 0.f);
    v.y = fmaxf(bf2f(mv.y) + bf2f(sv.y), 0.f);
    v.z = fmaxf(bf2f(mv.z) + bf2f(sv.z), 0.f);
    v.w = fmaxf(bf2f(mv.w) + bf2f(sv.w), 0.f);
    *(float4*)&Ah[r * APAD + 4 * c] = v;
  }
  __syncthreads();

  const int tx = tid & 7;
  const int ty = tid >> 3;
  const int arow = ty * 4;

  float4 an[4], as[4];
#pragma unroll
  for (int r = 0; r < 4; ++r) {
    an[r] = make_float4(0.f, 0.f, 0.f, 0.f);
    as[r] = make_float4(0.f, 0.f, 0.f, 0.f);
  }

#pragma unroll 1
  for (int k4 = 0; k4 < 16; ++k4) {
    float4 wn0 = *(const float4*)&Wn[(4 * k4 + 0) * 32 + 4 * tx];
    float4 wn1 = *(const float4*)&Wn[(4 * k4 + 1) * 32 + 4 * tx];
    float4 wn2 = *(const float4*)&Wn[(4 * k4 + 2) * 32 + 4 * tx];
    float4 wn3 = *(const float4*)&Wn[(4 * k4 + 3) * 32 + 4 * tx];
    float4 ws0 = *(const float4*)&Ws[(4 * k4 + 0) * 32 + 4 * tx];
    float4 ws1 = *(const float4*)&Ws[(4 * k4 + 1) * 32 + 4 * tx];
    float4 ws2 = *(const float4*)&Ws[(4 * k4 + 2) * 32 + 4 * tx];
    float4 ws3 = *(const float4*)&Ws[(4 * k4 + 3) * 32 + 4 * tx];
#pragma unroll
    for (int r = 0; r < 4; ++r) {
      float4 a = *(const float4*)&Ah[(arow + r) * APAD + 4 * k4];
      fma4(a.x, wn0, an[r]);
      fma4(a.y, wn1, an[r]);
      fma4(a.z, wn2, an[r]);
      fma4(a.w, wn3, an[r]);
      fma4(a.x, ws0, as[r]);
      fma4(a.y, ws1, as[r]);
      fma4(a.z, ws2, as[r]);
      fma4(a.w, ws3, as[r]);
    }
  }

  const float4 bv = *(const float4*)&b2[4 * tx];
#pragma unroll
  for (int r = 0; r < 4; ++r) {
    int row = row0 + arow + r;
    if (row < M) {
      float4 o;
      o.x = as[r].x + bv.x;
      o.y = as[r].y + bv.y;
      o.z = as[r].z + bv.z;
      o.w = as[r].w + bv.w;
      *(float4*)&hs[(long long)row * 32 + 4 * tx] = o;
      hnb8[(size_t)row * 8 + tx] =
          packfp8x4(an[r].x, an[r].y, an[r].z, an[r].w);
    }
  }
}

// ---------------------------------------------------------------------------
// gather2: out[node][:] = mean_j fp8decode(hnb8[ssrc[j]][:]) + hs[node][:]
// Row = 32 fp8 = 32 B; table 3.2 MB -> L2-resident. P=2 lanes/node.
// ---------------------------------------------------------------------------
__global__ __launch_bounds__(256) void gather2_k(
    const uint4* __restrict__ valb4, const int* __restrict__ ssrc,
    const uint2* __restrict__ rows2, const float* __restrict__ base,
    float* __restrict__ out, int N) {
  constexpr int P = 2;
  const int node = blockIdx.x * 128 + threadIdx.x / P;
  const int p = threadIdx.x & 1;
  if (node >= N) return;
  const uint2 be = rows2[node];
  const unsigned beg = be.x, end = be.y;

  float acc[16];
#pragma unroll
  for (int q = 0; q < 16; ++q) acc[q] = 0.f;

  unsigned j = beg;
  for (; j + 8 <= end; j += 8) {
    int sn[8];
#pragma unroll
    for (int i = 0; i < 8; ++i) sn[i] = ssrc[j + i];
    uint4 u[8];
#pragma unroll
    for (int i = 0; i < 8; ++i) u[i] = valb4[(size_t)sn[i] * P + p];
#pragma unroll
    for (int i = 0; i < 8; ++i) {
      v2f f0 = __builtin_amdgcn_cvt_pk_f32_fp8((int)u[i].x, false);
      v2f f1 = __builtin_amdgcn_cvt_pk_f32_fp8((int)u[i].x, true);
      v2f f2 = __builtin_amdgcn_cvt_pk_f32_fp8((int)u[i].y, false);
      v2f f3 = __builtin_amdgcn_cvt_pk_f32_fp8((int)u[i].y, true);
      v2f f4 = __builtin_amdgcn_cvt_pk_f32_fp8((int)u[i].z, false);
      v2f f5 = __builtin_amdgcn_cvt_pk_f32_fp8((int)u[i].z, true);
      v2f f6 = __builtin_amdgcn_cvt_pk_f32_fp8((int)u[i].w, false);
      v2f f7 = __builtin_amdgcn_cvt_pk_f32_fp8((int)u[i].w, true);
      acc[0] += f0[0];  acc[1] += f0[1];
      acc[2] += f1[0];  acc[3] += f1[1];
      acc[4] += f2[0];  acc[5] += f2[1];
      acc[6] += f3[0];  acc[7] += f3[1];
      acc[8] += f4[0];  acc[9] += f4[1];
      acc[10] += f5[0]; acc[11] += f5[1];
      acc[12] += f6[0]; acc[13] += f6[1];
      acc[14] += f7[0]; acc[15] += f7[1];
    }
  }
  if (j < end) {
    const unsigned last = end - 1;
    int sn[8];
#pragma unroll
    for (int i = 0; i < 8; ++i) {
      unsigned jj = j + i;
      sn[i] = ssrc[jj < last ? jj : last];
    }
    uint4 u[8];
#pragma unroll
    for (int i = 0; i < 8; ++i) u[i] = valb4[(size_t)sn[i] * P + p];
#pragma unroll
    for (int i = 0; i < 8; ++i) {
      float w = ((j + i) < end) ? 1.f : 0.f;
      v2f f0 = __builtin_amdgcn_cvt_pk_f32_fp8((int)u[i].x, false);
      v2f f1 = __builtin_amdgcn_cvt_pk_f32_fp8((int)u[i].x, true);
      v2f f2 = __builtin_amdgcn_cvt_pk_f32_fp8((int)u[i].y, false);
      v2f f3 = __builtin_amdgcn_cvt_pk_f32_fp8((int)u[i].y, true);
      v2f f4 = __builtin_amdgcn_cvt_pk_f32_fp8((int)u[i].z, false);
      v2f f5 = __builtin_amdgcn_cvt_pk_f32_fp8((int)u[i].z, true);
      v2f f6 = __builtin_amdgcn_cvt_pk_f32_fp8((int)u[i].w, false);
      v2f f7 = __builtin_amdgcn_cvt_pk_f32_fp8((int)u[i].w, true);
      acc[0] = fmaf(w, f0[0], acc[0]);   acc[1] = fmaf(w, f0[1], acc[1]);
      acc[2] = fmaf(w, f1[0], acc[2]);   acc[3] = fmaf(w, f1[1], acc[3]);
      acc[4] = fmaf(w, f2[0], acc[4]);   acc[5] = fmaf(w, f2[1], acc[5]);
      acc[6] = fmaf(w, f3[0], acc[6]);   acc[7] = fmaf(w, f3[1], acc[7]);
      acc[8] = fmaf(w, f4[0], acc[8]);   acc[9] = fmaf(w, f4[1], acc[9]);
      acc[10] = fmaf(w, f5[0], acc[10]); acc[11] = fmaf(w, f5[1], acc[11]);
      acc[12] = fmaf(w, f6[0], acc[12]); acc[13] = fmaf(w, f6[1], acc[13]);
      acc[14] = fmaf(w, f7[0], acc[14]); acc[15] = fmaf(w, f7[1], acc[15]);
    }
  }

  const unsigned dg = end - beg;
  const float inv = dg ? 1.f / (float)dg : 0.f;
  const size_t o = (size_t)node * 32 + 16 * p;
#pragma unroll
  for (int q4 = 0; q4 < 4; ++q4) {
    float4 bv = *(const float4*)&base[o + 4 * q4];
    float4 ov;
    ov.x = acc[4 * q4 + 0] * inv + bv.x;
    ov.y = acc[4 * q4 + 1] * inv + bv.y;
    ov.z = acc[4 * q4 + 2] * inv + bv.z;
    ov.w = acc[4 * q4 + 3] * inv + bv.w;
    *(float4*)&out[o + 4 * q4] = ov;
  }
}

extern "C" void kernel_launch(void* const* d_in, const int* in_sizes, int n_in,
                              void* d_out, int out_size, void* d_ws,
                              size_t ws_size, hipStream_t stream) {
  const float* x   = (const float*)d_in[0];
  const int*   ei  = (const int*)d_in[1];  // [2, E]: row0 = src, row1 = dst
  const float* W1n = (const float*)d_in[2];
  const float* W1s = (const float*)d_in[3];
  const float* b1  = (const float*)d_in[4];
  const float* W2n = (const float*)d_in[5];
  const float* W2s = (const float*)d_in[6];
  const float* b2  = (const float*)d_in[7];
  float* out = (float*)d_out;

  const int E = in_sizes[1] / 2;  // 1,600,000
  const int M = N_NODES;
  const int* src = ei;
  const int* dst = ei + E;

  // Workspace layout (bytes):
  //   ep    @ 0           12,845,056  (NB*CAP u32; layer2: hnb8 fp8 Mx32 aliases)
  //   ssrc  @ 12,845,056  12,845,056
  //   rows2 @ 25,690,112     802,816
  //   bcur  @ 26,492,928       3,136
  //   xnb8  @ 26,496,064   6,400,000  (fp8 M x 64)
  //   xsb   @ 32,896,064  12,800,000  (bf16 M x 64)
  //   mean1 @ 45,696,064  12,800,000  (bf16 M x 64)
  //   hs    @ 58,496,064  12,800,000  (f32 M x 32)
  char* wsb = (char*)d_ws;
  unsigned*       ep    = (unsigned*)(wsb);
  int*            ssrc  = (int*)(wsb + 12845056);
  uint2*          rows2 = (uint2*)(wsb + 25690112);
  unsigned*       bcur  = (unsigned*)(wsb + 26492928);
  unsigned*       xnb8  = (unsigned*)(wsb + 26496064);
  unsigned short* xsb   = (unsigned short*)(wsb + 32896064);
  unsigned short* mean1 = (unsigned short*)(wsb + 45696064);
  float*          hs    = (float*)(wsb + 58496064);
  unsigned*       hnb8  = (unsigned*)(wsb);  // aliases ep (dead after fused1)

  // 1) zero bucket cursors (3 KB)
  hipMemsetAsync(bcur, 0, NB * 4, stream);
  // 2) scatter edges into static bucket regions (391 blocks: all CUs busy)
  bscatter_k<<<(E + EPB - 1) / EPB, 512, 0, stream>>>(src, dst, bcur, ep, E);
  // 3) fused: layer-1 dual-GEMM (xn fp8, xs bf16) + per-bucket counting sort
  fused1_k<<<GB1 + NB, 256, 0, stream>>>(x, W1n, W1s, b1, xnb8, xsb, ep, bcur,
                                         ssrc, rows2, M);
  // 4) mean1(bf16) = mean(fp8(xn)[src])  -- 64 B rows, one line per edge
  gather1_k<<<(M + 63) / 64, 256, 0, stream>>>((const uint4*)xnb8, ssrc, rows2,
                                               (uint4*)mean1, M);
  // 5) gemm2 stages relu(mean1+xs); hn(fp8)/hs = Ah@{W2n,W2s}+b2
  gemm2_k<<<(M + 127) / 128, 256, 0, stream>>>(mean1, xsb, W2n, W2s, b2, hnb8,
                                               hs, M);
  // 6) out = mean(fp8(hn)[src]) + hs
  gather2_k<<<(M + 127) / 128, 256, 0, stream>>>((const uint4*)hnb8, ssrc,
                                                 rows2, hs, out, M);
}